// Round 5
// baseline (1695.953 us; speedup 1.0000x reference)
//
#include <hip/hip_runtime.h>

#define NQ 64
#define ND 50000
#define QTOK 32
#define DTOK 16
#define EMB 768
#define HID 512

typedef short s16x8 __attribute__((ext_vector_type(8)));
typedef float f32x4 __attribute__((ext_vector_type(4)));

// ---------- bf16 helpers (RNE) ----------
__device__ __forceinline__ unsigned short f2bf(float f) {
    union { float f; unsigned u; } x; x.f = f;
    unsigned r = x.u + 0x7fffu + ((x.u >> 16) & 1u);
    return (unsigned short)(r >> 16);
}
__device__ __forceinline__ float bf2f(unsigned short h) {
    union { unsigned u; float f; } x; x.u = ((unsigned)h) << 16;
    return x.f;
}
// activation stream (hi,lo,hi): pair (va,vb) -> 3 uints
__device__ __forceinline__ void pack2A(float va, float vb, unsigned& w0, unsigned& w1, unsigned& w2) {
    unsigned ha = f2bf(va); unsigned la = f2bf(va - bf2f((unsigned short)ha));
    unsigned hb = f2bf(vb); unsigned lb = f2bf(vb - bf2f((unsigned short)hb));
    w0 = ha | (la << 16);
    w1 = ha | (hb << 16);
    w2 = lb | (hb << 16);
}
// weight stream (hi,hi,lo): pair (va,vb) -> 3 uints
__device__ __forceinline__ void pack2B(float va, float vb, unsigned& w0, unsigned& w1, unsigned& w2) {
    unsigned ha = f2bf(va); unsigned la = f2bf(va - bf2f((unsigned short)ha));
    unsigned hb = f2bf(vb); unsigned lb = f2bf(vb - bf2f((unsigned short)hb));
    w0 = ha | (ha << 16);
    w1 = la | (hb << 16);
    w2 = hb | (lb << 16);
}

__device__ __forceinline__ void gload_lds16(const void* g, void* l) {
    __builtin_amdgcn_global_load_lds(
        (const __attribute__((address_space(1))) void*)g,
        (__attribute__((address_space(3))) void*)l, 16, 0, 0);
}

// ---------------- fp32 mean-pool (query path) ----------------
__global__ void pool_kernel(const float* __restrict__ in, float* __restrict__ out, int T) {
    int r = blockIdx.x;
    int t = threadIdx.x;  // 0..191
    const float4* ip = (const float4*)in + (size_t)r * T * (EMB / 4);
    float4 acc = make_float4(0.f, 0.f, 0.f, 0.f);
    for (int i = 0; i < T; ++i) {
        float4 v = ip[(size_t)i * (EMB / 4) + t];
        acc.x += v.x; acc.y += v.y; acc.z += v.z; acc.w += v.w;
    }
    float s = 1.0f / (float)T;
    acc.x *= s; acc.y *= s; acc.z *= s; acc.w *= s;
    ((float4*)out)[(size_t)r * (EMB / 4) + t] = acc;
}

// ---------------- doc mean-pool -> augmented bf16 [rows][3*EMB] ----------------
__global__ void pool_aug(const float* __restrict__ in, ushort* __restrict__ out) {
    int r = blockIdx.x, t = threadIdx.x;  // 192 threads x 4 floats
    const float4* ip = (const float4*)in + (size_t)r * DTOK * (EMB / 4) + t;
    float4 a = make_float4(0.f, 0.f, 0.f, 0.f);
    #pragma unroll
    for (int i = 0; i < DTOK; ++i) {
        float4 v = ip[(size_t)i * (EMB / 4)];
        a.x += v.x; a.y += v.y; a.z += v.z; a.w += v.w;
    }
    const float s = 1.0f / (float)DTOK;
    unsigned w0, w1, w2, w3, w4, w5;
    pack2A(a.x * s, a.y * s, w0, w1, w2);
    pack2A(a.z * s, a.w * s, w3, w4, w5);
    uint2* q = (uint2*)(out + (size_t)r * (3 * EMB) + t * 12);
    q[0] = make_uint2(w0, w1); q[1] = make_uint2(w2, w3); q[2] = make_uint2(w4, w5);
}

// ---------------- weight convert: W[K][512] fp32 -> Wp[512][3K] bf16 (hi,hi,lo) ----------------
__global__ void wconv(const float* __restrict__ W, ushort* __restrict__ Wp, int K) {
    int n = blockIdx.x;  // 512 blocks
    for (int k = threadIdx.x; k < K; k += blockDim.x) {
        float v = W[(size_t)k * HID + n];
        unsigned short hi = f2bf(v);
        unsigned short lo = f2bf(v - bf2f(hi));
        ushort* p = Wp + (size_t)n * 3 * K + 3 * k;
        p[0] = hi; p[1] = hi; p[2] = lo;
    }
}

// ---------------- doc-path MFMA GEMM: 256x256 tile, 8 waves, XCD-paired grid ----------------
// Grid MUST be 392 blocks (=196 row-panels x 2 col-panels, 392 = 8*49).
// MODE 0: fp32 out[M][HID] = acc + bias
// MODE 1: relu(acc+bias) -> augmented bf16 (hi,lo,hi) out[M][3*HID]
template <int MODE>
__global__ __launch_bounds__(512) void mfma_gemm3(const ushort* __restrict__ A,
                                                  const ushort* __restrict__ B,
                                                  const float* __restrict__ bias,
                                                  void* __restrict__ out,
                                                  int M, int K2) {
    __shared__ ushort As[256 * 64];  // 32 KB
    __shared__ ushort Bs[256 * 64];  // 32 KB  (total exactly 64 KB)
    // XCD pairing: consecutive HW dispatch ids round-robin XCDs; map so the two
    // col-blocks of one row-panel land on the same XCD (d and d+? share d&7).
    const int d  = blockIdx.x;
    const int pr = (d & 7) * 49 + (d >> 3);   // bijective over [0,392)
    const int bm = (pr >> 1) * 256;
    const int bn = (pr & 1) * 256;
    const int tid = threadIdx.x;
    const int lane = tid & 63;
    const int wave = tid >> 6;      // 0..7
    const int wr = wave >> 2;       // 0..1 : 128-row panel
    const int wc = wave & 3;        // 0..3 : 64-col panel
    f32x4 acc[8][4] = {};

    for (int k0 = 0; k0 < K2; k0 += 64) {
        #pragma unroll
        for (int c = 0; c < 4; ++c) {   // stage A: 32KB
            int idx = c * 512 + tid;
            int row = idx >> 3, s = idx & 7;
            int gr = bm + row; if (gr >= M) gr = M - 1;
            int ks = (s ^ (row & 7)) << 3;
            gload_lds16(A + (size_t)gr * K2 + k0 + ks, As + idx * 8);
        }
        #pragma unroll
        for (int c = 0; c < 4; ++c) {   // stage B: 32KB (cols bn..bn+255 < 512 always valid)
            int idx = c * 512 + tid;
            int n = idx >> 3, s = idx & 7;
            int ks = (s ^ (n & 7)) << 3;
            gload_lds16(B + (size_t)(bn + n) * K2 + k0 + ks, Bs + idx * 8);
        }
        __syncthreads();

        #pragma unroll
        for (int kk = 0; kk < 2; ++kk) {
            const int sp = kk * 4 + (lane >> 4);
            s16x8 b[4];
            #pragma unroll
            for (int j = 0; j < 4; ++j) {
                int n = wc * 64 + j * 16 + (lane & 15);
                b[j] = *(const s16x8*)(Bs + n * 64 + ((sp ^ (n & 7)) << 3));
            }
            #pragma unroll
            for (int i = 0; i < 8; ++i) {
                int r = wr * 128 + i * 16 + (lane & 15);
                s16x8 a = *(const s16x8*)(As + r * 64 + ((sp ^ (r & 7)) << 3));
                #pragma unroll
                for (int j = 0; j < 4; ++j)
                    acc[i][j] = __builtin_amdgcn_mfma_f32_16x16x32_bf16(a, b[j], acc[i][j], 0, 0, 0);
            }
        }
        __syncthreads();
    }

    // epilogue: C/D layout col=lane&15, row=(lane>>4)*4+reg
    #pragma unroll
    for (int j = 0; j < 4; ++j) {
        int col = bn + wc * 64 + j * 16 + (lane & 15);   // < 512
        float bv = bias[col];
        #pragma unroll
        for (int i = 0; i < 8; ++i) {
            #pragma unroll
            for (int r = 0; r < 4; ++r) {
                int grow = bm + wr * 128 + i * 16 + ((lane >> 4) << 2) + r;
                if (grow >= M) continue;
                float v = acc[i][j][r] + bv;
                if (MODE == 1) {
                    v = fmaxf(v, 0.0f);
                    unsigned short hi = f2bf(v);
                    unsigned short lo = f2bf(v - bf2f(hi));
                    ushort* op = (ushort*)out + (size_t)grow * (3 * HID) + 3 * col;
                    op[0] = hi; op[1] = lo; op[2] = hi;
                } else {
                    ((float*)out)[(size_t)grow * HID + col] = v;
                }
            }
        }
    }
}

// ---------------- scores MFMA GEMM (round-3 kernel, MODE 2 only) ----------------
__global__ __launch_bounds__(512) void mfma_scores(const ushort* __restrict__ A,
                                                   const ushort* __restrict__ B,
                                                   float* __restrict__ out,
                                                   int M, int N_B, int K2, long ldo,
                                                   const float* __restrict__ temp) {
    __shared__ ushort As[128 * 64];
    __shared__ ushort Bs[256 * 64];
    const int bm = blockIdx.x * 128;
    const int bn = blockIdx.y * 256;
    const int tid = threadIdx.x;
    const int lane = tid & 63;
    const int wave = tid >> 6;
    const int wr = wave >> 2;
    const int wc = wave & 3;
    f32x4 acc[4][4] = {};

    for (int k0 = 0; k0 < K2; k0 += 64) {
        #pragma unroll
        for (int c = 0; c < 2; ++c) {
            int idx = c * 512 + tid;
            int row = idx >> 3, s = idx & 7;
            int gr = bm + row; if (gr >= M) gr = M - 1;
            int ks = (s ^ (row & 7)) << 3;
            gload_lds16(A + (size_t)gr * K2 + k0 + ks, As + idx * 8);
        }
        #pragma unroll
        for (int c = 0; c < 4; ++c) {
            int idx = c * 512 + tid;
            int n = idx >> 3, s = idx & 7;
            int gn = bn + n; if (gn >= N_B) gn = N_B - 1;
            int ks = (s ^ (n & 7)) << 3;
            gload_lds16(B + (size_t)gn * K2 + k0 + ks, Bs + idx * 8);
        }
        __syncthreads();

        #pragma unroll
        for (int kk = 0; kk < 2; ++kk) {
            const int sp = kk * 4 + (lane >> 4);
            s16x8 a[4], b[4];
            #pragma unroll
            for (int i = 0; i < 4; ++i) {
                int r = wr * 64 + i * 16 + (lane & 15);
                a[i] = *(const s16x8*)(As + r * 64 + ((sp ^ (r & 7)) << 3));
            }
            #pragma unroll
            for (int j = 0; j < 4; ++j) {
                int n = wc * 64 + j * 16 + (lane & 15);
                b[j] = *(const s16x8*)(Bs + n * 64 + ((sp ^ (n & 7)) << 3));
            }
            #pragma unroll
            for (int i = 0; i < 4; ++i)
                #pragma unroll
                for (int j = 0; j < 4; ++j)
                    acc[i][j] = __builtin_amdgcn_mfma_f32_16x16x32_bf16(a[i], b[j], acc[i][j], 0, 0, 0);
        }
        __syncthreads();
    }

    float invT = 1.0f / temp[0];
    #pragma unroll
    for (int j = 0; j < 4; ++j) {
        int gcol = bn + wc * 64 + j * 16 + (lane & 15);
        #pragma unroll
        for (int i = 0; i < 4; ++i)
            #pragma unroll
            for (int r = 0; r < 4; ++r) {
                int grow = bm + wr * 64 + i * 16 + ((lane >> 4) << 2) + r;
                if (grow < M && gcol < N_B)
                    out[(size_t)grow * ldo + gcol] = acc[i][j][r] * invT;
            }
    }
}

// ---------------- in-place fp32 LayerNorm (query path) ----------------
__global__ __launch_bounds__(256) void ln_kernel(float* __restrict__ x,
                                                 const float* __restrict__ g,
                                                 const float* __restrict__ be, int M) {
    int wv = threadIdx.x >> 6, lane = threadIdx.x & 63;
    int row = blockIdx.x * 4 + wv;
    if (row >= M) return;
    float4* p = (float4*)(x + (size_t)row * HID);
    float4 a = p[lane * 2], b = p[lane * 2 + 1];
    float s  = a.x + a.y + a.z + a.w + b.x + b.y + b.z + b.w;
    float sq = a.x*a.x + a.y*a.y + a.z*a.z + a.w*a.w
             + b.x*b.x + b.y*b.y + b.z*b.z + b.w*b.w;
    #pragma unroll
    for (int o = 32; o > 0; o >>= 1) { s += __shfl_xor(s, o); sq += __shfl_xor(sq, o); }
    float mu  = s * (1.0f / HID);
    float var = sq * (1.0f / HID) - mu * mu;
    float r   = rsqrtf(var + 1e-5f);
    const float4* gp = (const float4*)g;
    const float4* bp = (const float4*)be;
    float4 g0 = gp[lane * 2], g1 = gp[lane * 2 + 1];
    float4 b0 = bp[lane * 2], b1 = bp[lane * 2 + 1];
    a.x = (a.x - mu) * r * g0.x + b0.x;  a.y = (a.y - mu) * r * g0.y + b0.y;
    a.z = (a.z - mu) * r * g0.z + b0.z;  a.w = (a.w - mu) * r * g0.w + b0.w;
    b.x = (b.x - mu) * r * g1.x + b1.x;  b.y = (b.y - mu) * r * g1.y + b1.y;
    b.z = (b.z - mu) * r * g1.z + b1.z;  b.w = (b.w - mu) * r * g1.w + b1.w;
    p[lane * 2] = a; p[lane * 2 + 1] = b;
}

// ---------------- LayerNorm fp32 -> augmented A-side bf16 [M][3*HID] ----------------
__global__ __launch_bounds__(256) void ln_aug(const float* __restrict__ x,
                                              const float* __restrict__ g,
                                              const float* __restrict__ be,
                                              ushort* __restrict__ out, int M) {
    int wv = threadIdx.x >> 6, lane = threadIdx.x & 63;
    int row = blockIdx.x * 4 + wv;
    if (row >= M) return;
    const float4* p = (const float4*)(x + (size_t)row * HID);
    float4 a = p[lane * 2], b = p[lane * 2 + 1];
    float s  = a.x + a.y + a.z + a.w + b.x + b.y + b.z + b.w;
    float sq = a.x*a.x + a.y*a.y + a.z*a.z + a.w*a.w
             + b.x*b.x + b.y*b.y + b.z*b.z + b.w*b.w;
    #pragma unroll
    for (int o = 32; o > 0; o >>= 1) { s += __shfl_xor(s, o); sq += __shfl_xor(sq, o); }
    float mu  = s * (1.0f / HID);
    float var = sq * (1.0f / HID) - mu * mu;
    float r   = rsqrtf(var + 1e-5f);
    const float4* gp = (const float4*)g;
    const float4* bp = (const float4*)be;
    float4 g0 = gp[lane * 2], g1 = gp[lane * 2 + 1];
    float4 b0 = bp[lane * 2], b1 = bp[lane * 2 + 1];
    float v0 = (a.x - mu) * r * g0.x + b0.x, v1 = (a.y - mu) * r * g0.y + b0.y;
    float v2 = (a.z - mu) * r * g0.z + b0.z, v3 = (a.w - mu) * r * g0.w + b0.w;
    float v4 = (b.x - mu) * r * g1.x + b1.x, v5 = (b.y - mu) * r * g1.y + b1.y;
    float v6 = (b.z - mu) * r * g1.z + b1.z, v7 = (b.w - mu) * r * g1.w + b1.w;
    unsigned w[12];
    pack2A(v0, v1, w[0], w[1], w[2]);
    pack2A(v2, v3, w[3], w[4], w[5]);
    pack2A(v4, v5, w[6], w[7], w[8]);
    pack2A(v6, v7, w[9], w[10], w[11]);
    uint4* q = (uint4*)(out + (size_t)row * (3 * HID) + lane * 24);
    q[0] = make_uint4(w[0], w[1], w[2], w[3]);
    q[1] = make_uint4(w[4], w[5], w[6], w[7]);
    q[2] = make_uint4(w[8], w[9], w[10], w[11]);
}

// ---------------- L2-normalize fp32 rows -> augmented B-side bf16 [M][3*HID] ----------------
__global__ __launch_bounds__(256) void l2_augB(const float* __restrict__ x,
                                               ushort* __restrict__ out, int M) {
    int wv = threadIdx.x >> 6, lane = threadIdx.x & 63;
    int row = blockIdx.x * 4 + wv;
    if (row >= M) return;
    const float4* p = (const float4*)(x + (size_t)row * HID);
    float4 a = p[lane * 2], b = p[lane * 2 + 1];
    float sq = a.x*a.x + a.y*a.y + a.z*a.z + a.w*a.w
             + b.x*b.x + b.y*b.y + b.z*b.z + b.w*b.w;
    #pragma unroll
    for (int o = 32; o > 0; o >>= 1) sq += __shfl_xor(sq, o);
    float n = sqrtf(sq);
    float r = 1.0f / fmaxf(n, 1e-12f);
    float v0 = a.x*r, v1 = a.y*r, v2 = a.z*r, v3 = a.w*r;
    float v4 = b.x*r, v5 = b.y*r, v6 = b.z*r, v7 = b.w*r;
    unsigned w[12];
    pack2B(v0, v1, w[0], w[1], w[2]);
    pack2B(v2, v3, w[3], w[4], w[5]);
    pack2B(v4, v5, w[6], w[7], w[8]);
    pack2B(v6, v7, w[9], w[10], w[11]);
    uint4* q = (uint4*)(out + (size_t)row * (3 * HID) + lane * 24);
    q[0] = make_uint4(w[0], w[1], w[2], w[3]);
    q[1] = make_uint4(w[4], w[5], w[6], w[7]);
    q[2] = make_uint4(w[8], w[9], w[10], w[11]);
}

// ---------------- in-place L2 normalize (query path fp32) ----------------
__global__ __launch_bounds__(256) void l2_kernel(float* __restrict__ x, int M) {
    int wv = threadIdx.x >> 6, lane = threadIdx.x & 63;
    int row = blockIdx.x * 4 + wv;
    if (row >= M) return;
    float4* p = (float4*)(x + (size_t)row * HID);
    float4 a = p[lane * 2], b = p[lane * 2 + 1];
    float sq = a.x*a.x + a.y*a.y + a.z*a.z + a.w*a.w
             + b.x*b.x + b.y*b.y + b.z*b.z + b.w*b.w;
    #pragma unroll
    for (int o = 32; o > 0; o >>= 1) sq += __shfl_xor(sq, o);
    float n = sqrtf(sq);
    float r = 1.0f / fmaxf(n, 1e-12f);
    a.x *= r; a.y *= r; a.z *= r; a.w *= r;
    b.x *= r; b.y *= r; b.z *= r; b.w *= r;
    p[lane * 2] = a; p[lane * 2 + 1] = b;
}

// ---------------- fp32 -> augmented A-side (queries) ----------------
__global__ __launch_bounds__(256) void fp32_augA(const float* __restrict__ x,
                                                 ushort* __restrict__ out, int M) {
    int wv = threadIdx.x >> 6, lane = threadIdx.x & 63;
    int row = blockIdx.x * 4 + wv;
    if (row >= M) return;
    const float4* p = (const float4*)(x + (size_t)row * HID);
    float4 a = p[lane * 2], b = p[lane * 2 + 1];
    unsigned w[12];
    pack2A(a.x, a.y, w[0], w[1], w[2]);
    pack2A(a.z, a.w, w[3], w[4], w[5]);
    pack2A(b.x, b.y, w[6], w[7], w[8]);
    pack2A(b.z, b.w, w[9], w[10], w[11]);
    uint4* q = (uint4*)(out + (size_t)row * (3 * HID) + lane * 24);
    q[0] = make_uint4(w[0], w[1], w[2], w[3]);
    q[1] = make_uint4(w[4], w[5], w[6], w[7]);
    q[2] = make_uint4(w[8], w[9], w[10], w[11]);
}

// ---------------- fp32 GEMM for the tiny query path ----------------
template <int RELU>
__global__ __launch_bounds__(256) void gemm_nn(const float* __restrict__ A,
                                               const float* __restrict__ W,
                                               const float* __restrict__ bias,
                                               float* __restrict__ C,
                                               int M, int K, int N) {
    __shared__ float As[16][68];
    __shared__ float Bs[16][64];
    const int bm = blockIdx.x * 64;
    const int bn = blockIdx.y * 64;
    const int tid = threadIdx.x;
    const int tx = tid & 15, ty = tid >> 4;
    float acc[4][4] = {};
    for (int k0 = 0; k0 < K; k0 += 16) {
        {
            int row = tid >> 2;
            int kk  = (tid & 3) << 2;
            int gr  = bm + row;
            float4 v = make_float4(0.f, 0.f, 0.f, 0.f);
            if (gr < M) v = *(const float4*)(A + (size_t)gr * K + k0 + kk);
            As[kk + 0][row] = v.x; As[kk + 1][row] = v.y;
            As[kk + 2][row] = v.z; As[kk + 3][row] = v.w;
        }
        {
            int n  = tid & 63;
            int kb = tid >> 6;
            #pragma unroll
            for (int q = 0; q < 4; ++q) {
                int kr = kb + q * 4;
                Bs[kr][n] = W[(size_t)(k0 + kr) * N + bn + n];
            }
        }
        __syncthreads();
        #pragma unroll
        for (int k = 0; k < 16; ++k) {
            float4 av = *(const float4*)&As[k][ty << 2];
            float4 bv = *(const float4*)&Bs[k][tx << 2];
            float a[4] = {av.x, av.y, av.z, av.w};
            float b[4] = {bv.x, bv.y, bv.z, bv.w};
            #pragma unroll
            for (int i = 0; i < 4; ++i)
                #pragma unroll
                for (int j = 0; j < 4; ++j)
                    acc[i][j] = fmaf(a[i], b[j], acc[i][j]);
        }
        __syncthreads();
    }
    #pragma unroll
    for (int i = 0; i < 4; ++i) {
        int gr = bm + (ty << 2) + i;
        if (gr >= M) continue;
        #pragma unroll
        for (int j = 0; j < 4; ++j) {
            int gc = bn + (tx << 2) + j;
            float v = acc[i][j] + bias[gc];
            if (RELU) v = fmaxf(v, 0.0f);
            C[(size_t)gr * N + gc] = v;
        }
    }
}

// ---------------- top-8 per row with lowest-index tie-break ----------------
__global__ __launch_bounds__(256) void topk_kernel(const float* __restrict__ scores,
                                                   float* __restrict__ out_scores,
                                                   int* __restrict__ out_idx, int N) {
    __shared__ float ls[2048];
    __shared__ int   li[2048];
    const int q   = blockIdx.x;
    const int tid = threadIdx.x;
    const float* row = scores + (size_t)q * N;
    float s[8]; int ix[8];
    #pragma unroll
    for (int i = 0; i < 8; ++i) { s[i] = -1e30f; ix[i] = 0x7fffffff; }
    for (int j = tid; j < N; j += 256) {
        float v = row[j];
        if (v > s[7]) {
            s[7] = v; ix[7] = j;
            #pragma unroll
            for (int t = 7; t > 0; --t) {
                bool sw = (s[t] > s[t-1]) || (s[t] == s[t-1] && ix[t] < ix[t-1]);
                if (sw) {
                    float tv = s[t]; s[t] = s[t-1]; s[t-1] = tv;
                    int   ti = ix[t]; ix[t] = ix[t-1]; ix[t-1] = ti;
                }
            }
        }
    }
    #pragma unroll
    for (int i = 0; i < 8; ++i) { ls[tid * 8 + i] = s[i]; li[tid * 8 + i] = ix[i]; }
    __syncthreads();
    for (int w = 64; w >= 1; w >>= 2) {
        if (tid < w) {
            #pragma unroll
            for (int i = 0; i < 8; ++i) { s[i] = -1e30f; ix[i] = 0x7fffffff; }
            #pragma unroll
            for (int c = 0; c < 32; ++c) {
                float v  = ls[tid * 32 + c];
                int   vi = li[tid * 32 + c];
                bool better = (v > s[7]) || (v == s[7] && vi < ix[7]);
                if (better) {
                    s[7] = v; ix[7] = vi;
                    #pragma unroll
                    for (int t = 7; t > 0; --t) {
                        bool sw = (s[t] > s[t-1]) || (s[t] == s[t-1] && ix[t] < ix[t-1]);
                        if (sw) {
                            float tv = s[t]; s[t] = s[t-1]; s[t-1] = tv;
                            int   ti = ix[t]; ix[t] = ix[t-1]; ix[t-1] = ti;
                        }
                    }
                }
            }
        }
        __syncthreads();
        if (tid < w) {
            #pragma unroll
            for (int i = 0; i < 8; ++i) { ls[tid * 8 + i] = s[i]; li[tid * 8 + i] = ix[i]; }
        }
        __syncthreads();
    }
    if (tid < 8) {
        out_scores[(size_t)q * 8 + tid] = ls[tid];
        out_idx[q * 8 + tid]            = li[tid];
    }
}

// ---------------- gather retrieved docs ----------------
__global__ __launch_bounds__(256) void gather_kernel(const float* __restrict__ docs,
                                                     const int* __restrict__ idx,
                                                     float* __restrict__ out) {
    const int b = blockIdx.x;
    const int d = idx[b];
    const float4* src = (const float4*)(docs + (size_t)d * DTOK * EMB);
    float4*       dst = (float4*)(out + (size_t)b * DTOK * EMB);
    for (int i = threadIdx.x; i < DTOK * EMB / 4; i += 256) dst[i] = src[i];
}

extern "C" void kernel_launch(void* const* d_in, const int* in_sizes, int n_in,
                              void* d_out, int out_size, void* d_ws, size_t ws_size,
                              hipStream_t stream) {
    const float* qe   = (const float*)d_in[0];
    const float* de   = (const float*)d_in[1];
    const float* qW1  = (const float*)d_in[2];
    const float* qb1  = (const float*)d_in[3];
    const float* qW2  = (const float*)d_in[4];
    const float* qb2  = (const float*)d_in[5];
    const float* qg   = (const float*)d_in[6];
    const float* qbe  = (const float*)d_in[7];
    const float* dW1  = (const float*)d_in[8];
    const float* db1  = (const float*)d_in[9];
    const float* dW2  = (const float*)d_in[10];
    const float* db2  = (const float*)d_in[11];
    const float* dg   = (const float*)d_in[12];
    const float* dbe  = (const float*)d_in[13];
    const float* pW   = (const float*)d_in[14];
    const float* pb   = (const float*)d_in[15];
    const float* temp = (const float*)d_in[16];

    float* out = (float*)d_out;

    // ---- workspace carve (~510 MB) ----
    char* w = (char*)d_ws;
    float*  scores = (float*)w;                 w += (size_t)NQ * ND * 4;
    ushort* W1p    = (ushort*)w;                w += (size_t)HID * 3 * EMB * 2;
    ushort* W2p    = (ushort*)w;                w += (size_t)HID * 3 * HID * 2;
    ushort* pWp    = (ushort*)w;                w += (size_t)HID * 3 * HID * 2;
    float*  qpool  = (float*)w;                 w += (size_t)NQ * EMB * 4;
    float*  qh1    = (float*)w;                 w += (size_t)NQ * HID * 4;
    float*  qh2    = (float*)w;                 w += (size_t)NQ * HID * 4;
    float*  qn     = (float*)w;                 w += (size_t)NQ * HID * 4;
    ushort* qaug   = (ushort*)w;                w += (size_t)NQ * 3 * HID * 2;
    int*    tidx   = (int*)w;                   w += 4096;
    ushort* pooled = (ushort*)w;                w += (size_t)ND * 3 * EMB * 2;      // 230.4 MB
    ushort* h1a    = (ushort*)w;                w += (size_t)ND * 3 * HID * 2;      // 153.6 MB
    float*  h2     = (float*)w;                 w += (size_t)ND * HID * 4;          // 102.4 MB
    ushort* lna    = pooled;   // LN-aug overwrites pooled (dead after GEMM1)
    float*  pproj  = h2;       // GEMM3 out overwrites h2 (dead after ln_aug)
    ushort* Daug   = h1a;      // l2_augB overwrites h1a (dead after GEMM2)

    // ---- weight conversion (tiny) ----
    wconv<<<HID, 256, 0, stream>>>(dW1, W1p, EMB);
    wconv<<<HID, 256, 0, stream>>>(dW2, W2p, HID);
    wconv<<<HID, 256, 0, stream>>>(pW,  pWp, HID);

    // ---- query path (fp32, tiny) ----
    pool_kernel<<<NQ, 192, 0, stream>>>(qe, qpool, QTOK);
    gemm_nn<1><<<dim3(1, 8), 256, 0, stream>>>(qpool, qW1, qb1, qh1, NQ, EMB, HID);
    gemm_nn<0><<<dim3(1, 8), 256, 0, stream>>>(qh1, qW2, qb2, qh2, NQ, HID, HID);
    ln_kernel<<<(NQ + 3) / 4, 256, 0, stream>>>(qh2, qg, qbe, NQ);
    gemm_nn<0><<<dim3(1, 8), 256, 0, stream>>>(qh2, pW, pb, qn, NQ, HID, HID);
    l2_kernel<<<(NQ + 3) / 4, 256, 0, stream>>>(qn, NQ);
    fp32_augA<<<(NQ + 3) / 4, 256, 0, stream>>>(qn, qaug, NQ);

    // ---- doc path, full-M single pass; 392 = 196 row-panels x 2 col-panels ----
    pool_aug<<<ND, 192, 0, stream>>>(de, pooled);
    mfma_gemm3<1><<<392, 512, 0, stream>>>(pooled, W1p, db1, h1a, ND, 3 * EMB);
    mfma_gemm3<0><<<392, 512, 0, stream>>>(h1a, W2p, db2, h2, ND, 3 * HID);
    ln_aug<<<(ND + 3) / 4, 256, 0, stream>>>(h2, dg, dbe, lna, ND);
    mfma_gemm3<0><<<392, 512, 0, stream>>>(lna, pWp, pb, pproj, ND, 3 * HID);
    l2_augB<<<(ND + 3) / 4, 256, 0, stream>>>(pproj, Daug, ND);

    // ---- scores: [64, ND] = qaug x Daug^T * (1/T) ----
    mfma_scores<<<dim3(1, (ND + 255) / 256), 512, 0, stream>>>(qaug, Daug, scores,
                                                               NQ, ND, 3 * HID, (long)ND, temp);

    // ---- top-k + gather ----
    topk_kernel<<<NQ, 256, 0, stream>>>(scores, out, tidx, ND);
    gather_kernel<<<NQ * 8, 256, 0, stream>>>(de, tidx, out + NQ * 8);
}

// Round 6
// 1604.287 us; speedup vs baseline: 1.0571x; 1.0571x over previous
//
#include <hip/hip_runtime.h>

#define NQ 64
#define ND 50000
#define QTOK 32
#define DTOK 16
#define EMB 768
#define HID 512

typedef short s16x8 __attribute__((ext_vector_type(8)));
typedef float f32x4 __attribute__((ext_vector_type(4)));

// ---------- bf16 helpers (RNE) ----------
__device__ __forceinline__ unsigned short f2bf(float f) {
    union { float f; unsigned u; } x; x.f = f;
    unsigned r = x.u + 0x7fffu + ((x.u >> 16) & 1u);
    return (unsigned short)(r >> 16);
}
__device__ __forceinline__ float bf2f(unsigned short h) {
    union { unsigned u; float f; } x; x.u = ((unsigned)h) << 16;
    return x.f;
}
__device__ __forceinline__ void packA1(float v, ushort* p) {  // A-side triple (hi,lo,hi)
    unsigned short hi = f2bf(v);
    unsigned short lo = f2bf(v - bf2f(hi));
    p[0] = hi; p[1] = lo; p[2] = hi;
}
__device__ __forceinline__ void packB1(float v, ushort* p) {  // B-side triple (hi,hi,lo)
    unsigned short hi = f2bf(v);
    unsigned short lo = f2bf(v - bf2f(hi));
    p[0] = hi; p[1] = hi; p[2] = lo;
}
// activation stream (hi,lo,hi): pair (va,vb) -> 3 uints
__device__ __forceinline__ void pack2A(float va, float vb, unsigned& w0, unsigned& w1, unsigned& w2) {
    unsigned ha = f2bf(va); unsigned la = f2bf(va - bf2f((unsigned short)ha));
    unsigned hb = f2bf(vb); unsigned lb = f2bf(vb - bf2f((unsigned short)hb));
    w0 = ha | (la << 16);
    w1 = ha | (hb << 16);
    w2 = lb | (hb << 16);
}
// weight stream (hi,hi,lo): pair (va,vb) -> 3 uints
__device__ __forceinline__ void pack2B(float va, float vb, unsigned& w0, unsigned& w1, unsigned& w2) {
    unsigned ha = f2bf(va); unsigned la = f2bf(va - bf2f((unsigned short)ha));
    unsigned hb = f2bf(vb); unsigned lb = f2bf(vb - bf2f((unsigned short)hb));
    w0 = ha | (ha << 16);
    w1 = la | (hb << 16);
    w2 = hb | (lb << 16);
}

__device__ __forceinline__ void gload_lds16(const void* g, void* l) {
    __builtin_amdgcn_global_load_lds(
        (const __attribute__((address_space(1))) void*)g,
        (__attribute__((address_space(3))) void*)l, 16, 0, 0);
}

// ---------------- mean-pool -> augmented A-side bf16 [rows][3*EMB] ----------------
__global__ void pool_aug(const float* __restrict__ in, ushort* __restrict__ out, int T) {
    int r = blockIdx.x, t = threadIdx.x;  // 192 threads x 4 floats
    const float4* ip = (const float4*)in + (size_t)r * T * (EMB / 4) + t;
    float4 a = make_float4(0.f, 0.f, 0.f, 0.f);
    for (int i = 0; i < T; ++i) {
        float4 v = ip[(size_t)i * (EMB / 4)];
        a.x += v.x; a.y += v.y; a.z += v.z; a.w += v.w;
    }
    const float s = 1.0f / (float)T;
    unsigned w0, w1, w2, w3, w4, w5;
    pack2A(a.x * s, a.y * s, w0, w1, w2);
    pack2A(a.z * s, a.w * s, w3, w4, w5);
    uint2* q = (uint2*)(out + (size_t)r * (3 * EMB) + t * 12);
    q[0] = make_uint2(w0, w1); q[1] = make_uint2(w2, w3); q[2] = make_uint2(w4, w5);
}

// ---------------- weight convert: W[K][512] fp32 -> Wp[512][3K] bf16 (hi,hi,lo) ----------------
__global__ void wconv(const float* __restrict__ W, ushort* __restrict__ Wp, int K) {
    int n = blockIdx.x;  // 512 blocks
    for (int k = threadIdx.x; k < K; k += blockDim.x) {
        float v = W[(size_t)k * HID + n];
        ushort* p = Wp + (size_t)n * 3 * K + 3 * k;
        packB1(v, p);
    }
}

// ---------------- doc MFMA GEMM: 128x256 tile, 8 waves, XCD-paired 1-D grid ----------------
// grid = npanels*2 blocks; bijective XCD map puts both 256-col panels of one
// 128-row A-panel on consecutive slots of the SAME XCD (A re-read -> L2 hit).
// MODE 0: fp32 out[M][HID] = acc + bias
// MODE 1: relu(acc+bias) -> augmented bf16 (hi,lo,hi) out[M][3*HID]
template <int MODE>
__global__ __launch_bounds__(512) void mfma_gemm2(const ushort* __restrict__ A,
                                                  const ushort* __restrict__ B,
                                                  const float* __restrict__ bias,
                                                  void* __restrict__ out,
                                                  int M, int K2) {
    __shared__ ushort As[128 * 64];  // 16KB
    __shared__ ushort Bs[256 * 64];  // 32KB (48KB total -> >=2 blocks/CU)
    // bijective XCD swizzle (m204): nwg = gridDim.x, XCD = d&7
    const int nwg = gridDim.x;
    const int d   = blockIdx.x;
    const int qq  = nwg >> 3, rr = nwg & 7;
    const int x   = d & 7, slot = d >> 3;
    const int base = (x < rr) ? x * (qq + 1) : rr * (qq + 1) + (x - rr) * qq;
    const int g   = base + slot;
    const int bm  = (g >> 1) * 128;
    const int bn  = (g & 1) * 256;
    const int tid = threadIdx.x;
    const int lane = tid & 63;
    const int wave = tid >> 6;
    const int wr = wave >> 2;        // 0..1 : 64-row panel
    const int wc = wave & 3;         // 0..3 : 64-col panel
    f32x4 acc[4][4] = {};

    for (int k0 = 0; k0 < K2; k0 += 64) {
        #pragma unroll
        for (int c = 0; c < 2; ++c) {   // stage A: 16KB
            int idx = c * 512 + tid;
            int row = idx >> 3, s = idx & 7;
            int gr = bm + row; if (gr >= M) gr = M - 1;
            int ks = (s ^ (row & 7)) << 3;
            gload_lds16(A + (size_t)gr * K2 + k0 + ks, As + idx * 8);
        }
        #pragma unroll
        for (int c = 0; c < 4; ++c) {   // stage B: 32KB (bn+n <= 511 always valid)
            int idx = c * 512 + tid;
            int n = idx >> 3, s = idx & 7;
            int ks = (s ^ (n & 7)) << 3;
            gload_lds16(B + (size_t)(bn + n) * K2 + k0 + ks, Bs + idx * 8);
        }
        __syncthreads();

        #pragma unroll
        for (int kk = 0; kk < 2; ++kk) {
            const int sp = kk * 4 + (lane >> 4);
            s16x8 a[4], b[4];
            #pragma unroll
            for (int i = 0; i < 4; ++i) {
                int r = wr * 64 + i * 16 + (lane & 15);
                a[i] = *(const s16x8*)(As + r * 64 + ((sp ^ (r & 7)) << 3));
            }
            #pragma unroll
            for (int j = 0; j < 4; ++j) {
                int n = wc * 64 + j * 16 + (lane & 15);
                b[j] = *(const s16x8*)(Bs + n * 64 + ((sp ^ (n & 7)) << 3));
            }
            #pragma unroll
            for (int i = 0; i < 4; ++i)
                #pragma unroll
                for (int j = 0; j < 4; ++j)
                    acc[i][j] = __builtin_amdgcn_mfma_f32_16x16x32_bf16(a[i], b[j], acc[i][j], 0, 0, 0);
        }
        __syncthreads();
    }

    // epilogue: C/D layout col=lane&15, row=(lane>>4)*4+reg
    #pragma unroll
    for (int j = 0; j < 4; ++j) {
        int col = bn + wc * 64 + j * 16 + (lane & 15);   // < 512
        float bv = bias[col];
        #pragma unroll
        for (int i = 0; i < 4; ++i) {
            #pragma unroll
            for (int r = 0; r < 4; ++r) {
                int grow = bm + wr * 64 + i * 16 + ((lane >> 4) << 2) + r;
                if (grow >= M) continue;
                float v = acc[i][j][r] + bv;
                if (MODE == 1) {
                    v = fmaxf(v, 0.0f);
                    ushort* op = (ushort*)out + (size_t)grow * (3 * HID) + 3 * col;
                    packA1(v, op);
                } else {
                    ((float*)out)[(size_t)grow * HID + col] = v;
                }
            }
        }
    }
}

// ---------------- scores MFMA GEMM ----------------
__global__ __launch_bounds__(512) void mfma_scores(const ushort* __restrict__ A,
                                                   const ushort* __restrict__ B,
                                                   float* __restrict__ out,
                                                   int M, int N_B, int K2, long ldo,
                                                   const float* __restrict__ temp) {
    __shared__ ushort As[128 * 64];
    __shared__ ushort Bs[256 * 64];
    const int bm = blockIdx.x * 128;
    const int bn = blockIdx.y * 256;
    const int tid = threadIdx.x;
    const int lane = tid & 63;
    const int wave = tid >> 6;
    const int wr = wave >> 2;
    const int wc = wave & 3;
    f32x4 acc[4][4] = {};

    for (int k0 = 0; k0 < K2; k0 += 64) {
        #pragma unroll
        for (int c = 0; c < 2; ++c) {
            int idx = c * 512 + tid;
            int row = idx >> 3, s = idx & 7;
            int gr = bm + row; if (gr >= M) gr = M - 1;
            int ks = (s ^ (row & 7)) << 3;
            gload_lds16(A + (size_t)gr * K2 + k0 + ks, As + idx * 8);
        }
        #pragma unroll
        for (int c = 0; c < 4; ++c) {
            int idx = c * 512 + tid;
            int n = idx >> 3, s = idx & 7;
            int gn = bn + n; if (gn >= N_B) gn = N_B - 1;
            int ks = (s ^ (n & 7)) << 3;
            gload_lds16(B + (size_t)gn * K2 + k0 + ks, Bs + idx * 8);
        }
        __syncthreads();

        #pragma unroll
        for (int kk = 0; kk < 2; ++kk) {
            const int sp = kk * 4 + (lane >> 4);
            s16x8 a[4], b[4];
            #pragma unroll
            for (int i = 0; i < 4; ++i) {
                int r = wr * 64 + i * 16 + (lane & 15);
                a[i] = *(const s16x8*)(As + r * 64 + ((sp ^ (r & 7)) << 3));
            }
            #pragma unroll
            for (int j = 0; j < 4; ++j) {
                int n = wc * 64 + j * 16 + (lane & 15);
                b[j] = *(const s16x8*)(Bs + n * 64 + ((sp ^ (n & 7)) << 3));
            }
            #pragma unroll
            for (int i = 0; i < 4; ++i)
                #pragma unroll
                for (int j = 0; j < 4; ++j)
                    acc[i][j] = __builtin_amdgcn_mfma_f32_16x16x32_bf16(a[i], b[j], acc[i][j], 0, 0, 0);
        }
        __syncthreads();
    }

    float invT = 1.0f / temp[0];
    #pragma unroll
    for (int j = 0; j < 4; ++j) {
        int gcol = bn + wc * 64 + j * 16 + (lane & 15);
        #pragma unroll
        for (int i = 0; i < 4; ++i)
            #pragma unroll
            for (int r = 0; r < 4; ++r) {
                int grow = bm + wr * 64 + i * 16 + ((lane >> 4) << 2) + r;
                if (grow < M && gcol < N_B)
                    out[(size_t)grow * ldo + gcol] = acc[i][j][r] * invT;
            }
    }
}

// ---------------- query-path fused MFMA GEMM (M=64, tile 64x512, 8 waves) ----------------
// EPI 0: relu(acc+bias) -> augA;  EPI 1: LayerNorm -> augA;  EPI 2: L2norm -> augA
template <int EPI>
__global__ __launch_bounds__(512) void gemmF(const ushort* __restrict__ A,
                                             const ushort* __restrict__ B,
                                             const float* __restrict__ bias,
                                             const float* __restrict__ gamma,
                                             const float* __restrict__ beta,
                                             ushort* __restrict__ out,
                                             int M, int K2) {
    __shared__ ushort As[64 * 64];
    __shared__ ushort Bs[512 * 64];
    __shared__ float red[2][8][64];
    __shared__ float mu_s[64], rs_s[64];
    const int tid = threadIdx.x;
    const int lane = tid & 63;
    const int wc = tid >> 6;   // 0..7 col panel
    f32x4 acc[4][4] = {};

    for (int k0 = 0; k0 < K2; k0 += 64) {
        {   // stage A: 8KB (one round)
            int row = tid >> 3, s = tid & 7;
            int gr = row; if (gr >= M) gr = M - 1;
            int ks = (s ^ (row & 7)) << 3;
            gload_lds16(A + (size_t)gr * K2 + k0 + ks, As + tid * 8);
        }
        #pragma unroll
        for (int c = 0; c < 8; ++c) {   // stage B: 64KB
            int idx = c * 512 + tid;
            int n = idx >> 3, s = idx & 7;
            int ks = (s ^ (n & 7)) << 3;
            gload_lds16(B + (size_t)n * K2 + k0 + ks, Bs + idx * 8);
        }
        __syncthreads();

        #pragma unroll
        for (int kk = 0; kk < 2; ++kk) {
            const int sp = kk * 4 + (lane >> 4);
            s16x8 a[4], b[4];
            #pragma unroll
            for (int i = 0; i < 4; ++i) {
                int r = i * 16 + (lane & 15);
                a[i] = *(const s16x8*)(As + r * 64 + ((sp ^ (r & 7)) << 3));
            }
            #pragma unroll
            for (int j = 0; j < 4; ++j) {
                int n = wc * 64 + j * 16 + (lane & 15);
                b[j] = *(const s16x8*)(Bs + n * 64 + ((sp ^ (n & 7)) << 3));
            }
            #pragma unroll
            for (int i = 0; i < 4; ++i)
                #pragma unroll
                for (int j = 0; j < 4; ++j)
                    acc[i][j] = __builtin_amdgcn_mfma_f32_16x16x32_bf16(a[i], b[j], acc[i][j], 0, 0, 0);
        }
        __syncthreads();
    }

    float bv[4];
    #pragma unroll
    for (int j = 0; j < 4; ++j) bv[j] = bias[wc * 64 + j * 16 + (lane & 15)];

    if (EPI == 1 || EPI == 2) {
        #pragma unroll
        for (int i = 0; i < 4; ++i)
            #pragma unroll
            for (int r = 0; r < 4; ++r) {
                float ps = 0.f, pq = 0.f;
                #pragma unroll
                for (int j = 0; j < 4; ++j) {
                    float v = acc[i][j][r] + bv[j];
                    ps += v; pq += v * v;
                }
                #pragma unroll
                for (int o = 1; o < 16; o <<= 1) {
                    ps += __shfl_xor(ps, o);
                    pq += __shfl_xor(pq, o);
                }
                if ((lane & 15) == 0) {
                    int rl = i * 16 + ((lane >> 4) << 2) + r;
                    red[0][wc][rl] = ps;
                    red[1][wc][rl] = pq;
                }
            }
        __syncthreads();
        if (tid < 64) {
            float s = 0.f, q = 0.f;
            #pragma unroll
            for (int w = 0; w < 8; ++w) { s += red[0][w][tid]; q += red[1][w][tid]; }
            if (EPI == 1) {
                float mu = s * (1.0f / 512.0f);
                float var = q * (1.0f / 512.0f) - mu * mu;
                mu_s[tid] = mu;
                rs_s[tid] = rsqrtf(var + 1e-5f);
            } else {
                mu_s[tid] = 0.0f;
                rs_s[tid] = 1.0f / fmaxf(sqrtf(q), 1e-12f);
            }
        }
        __syncthreads();
    }

    float gl[4], bt[4];
    if (EPI == 1) {
        #pragma unroll
        for (int j = 0; j < 4; ++j) {
            int c = wc * 64 + j * 16 + (lane & 15);
            gl[j] = gamma[c]; bt[j] = beta[c];
        }
    }

    #pragma unroll
    for (int i = 0; i < 4; ++i)
        #pragma unroll
        for (int r = 0; r < 4; ++r) {
            int rl = i * 16 + ((lane >> 4) << 2) + r;
            if (rl >= M) continue;
            #pragma unroll
            for (int j = 0; j < 4; ++j) {
                int col = wc * 64 + j * 16 + (lane & 15);
                float v = acc[i][j][r] + bv[j];
                if (EPI == 0) v = fmaxf(v, 0.0f);
                else if (EPI == 1) v = (v - mu_s[rl]) * rs_s[rl] * gl[j] + bt[j];
                else v = v * rs_s[rl];
                packA1(v, out + (size_t)rl * (3 * HID) + 3 * col);
            }
        }
}

// ---------------- LayerNorm fp32 -> augmented A-side bf16 [M][3*HID] ----------------
__global__ __launch_bounds__(256) void ln_aug(const float* __restrict__ x,
                                              const float* __restrict__ g,
                                              const float* __restrict__ be,
                                              ushort* __restrict__ out, int M) {
    int wv = threadIdx.x >> 6, lane = threadIdx.x & 63;
    int row = blockIdx.x * 4 + wv;
    if (row >= M) return;
    const float4* p = (const float4*)(x + (size_t)row * HID);
    float4 a = p[lane * 2], b = p[lane * 2 + 1];
    float s  = a.x + a.y + a.z + a.w + b.x + b.y + b.z + b.w;
    float sq = a.x*a.x + a.y*a.y + a.z*a.z + a.w*a.w
             + b.x*b.x + b.y*b.y + b.z*b.z + b.w*b.w;
    #pragma unroll
    for (int o = 32; o > 0; o >>= 1) { s += __shfl_xor(s, o); sq += __shfl_xor(sq, o); }
    float mu  = s * (1.0f / HID);
    float var = sq * (1.0f / HID) - mu * mu;
    float r   = rsqrtf(var + 1e-5f);
    const float4* gp = (const float4*)g;
    const float4* bp = (const float4*)be;
    float4 g0 = gp[lane * 2], g1 = gp[lane * 2 + 1];
    float4 b0 = bp[lane * 2], b1 = bp[lane * 2 + 1];
    float v0 = (a.x - mu) * r * g0.x + b0.x, v1 = (a.y - mu) * r * g0.y + b0.y;
    float v2 = (a.z - mu) * r * g0.z + b0.z, v3 = (a.w - mu) * r * g0.w + b0.w;
    float v4 = (b.x - mu) * r * g1.x + b1.x, v5 = (b.y - mu) * r * g1.y + b1.y;
    float v6 = (b.z - mu) * r * g1.z + b1.z, v7 = (b.w - mu) * r * g1.w + b1.w;
    unsigned w[12];
    pack2A(v0, v1, w[0], w[1], w[2]);
    pack2A(v2, v3, w[3], w[4], w[5]);
    pack2A(v4, v5, w[6], w[7], w[8]);
    pack2A(v6, v7, w[9], w[10], w[11]);
    uint4* q = (uint4*)(out + (size_t)row * (3 * HID) + lane * 24);
    q[0] = make_uint4(w[0], w[1], w[2], w[3]);
    q[1] = make_uint4(w[4], w[5], w[6], w[7]);
    q[2] = make_uint4(w[8], w[9], w[10], w[11]);
}

// ---------------- L2-normalize fp32 rows -> augmented B-side bf16 [M][3*HID] ----------------
__global__ __launch_bounds__(256) void l2_augB(const float* __restrict__ x,
                                               ushort* __restrict__ out, int M) {
    int wv = threadIdx.x >> 6, lane = threadIdx.x & 63;
    int row = blockIdx.x * 4 + wv;
    if (row >= M) return;
    const float4* p = (const float4*)(x + (size_t)row * HID);
    float4 a = p[lane * 2], b = p[lane * 2 + 1];
    float sq = a.x*a.x + a.y*a.y + a.z*a.z + a.w*a.w
             + b.x*b.x + b.y*b.y + b.z*b.z + b.w*b.w;
    #pragma unroll
    for (int o = 32; o > 0; o >>= 1) sq += __shfl_xor(sq, o);
    float n = sqrtf(sq);
    float r = 1.0f / fmaxf(n, 1e-12f);
    float v0 = a.x*r, v1 = a.y*r, v2 = a.z*r, v3 = a.w*r;
    float v4 = b.x*r, v5 = b.y*r, v6 = b.z*r, v7 = b.w*r;
    unsigned w[12];
    pack2B(v0, v1, w[0], w[1], w[2]);
    pack2B(v2, v3, w[3], w[4], w[5]);
    pack2B(v4, v5, w[6], w[7], w[8]);
    pack2B(v6, v7, w[9], w[10], w[11]);
    uint4* q = (uint4*)(out + (size_t)row * (3 * HID) + lane * 24);
    q[0] = make_uint4(w[0], w[1], w[2], w[3]);
    q[1] = make_uint4(w[4], w[5], w[6], w[7]);
    q[2] = make_uint4(w[8], w[9], w[10], w[11]);
}

// ---------------- top-8 per row with lowest-index tie-break ----------------
__global__ __launch_bounds__(256) void topk_kernel(const float* __restrict__ scores,
                                                   float* __restrict__ out_scores,
                                                   int* __restrict__ out_idx, int N) {
    __shared__ float ls[2048];
    __shared__ int   li[2048];
    const int q   = blockIdx.x;
    const int tid = threadIdx.x;
    const float* row = scores + (size_t)q * N;
    float s[8]; int ix[8];
    #pragma unroll
    for (int i = 0; i < 8; ++i) { s[i] = -1e30f; ix[i] = 0x7fffffff; }
    for (int j = tid; j < N; j += 256) {
        float v = row[j];
        if (v > s[7]) {
            s[7] = v; ix[7] = j;
            #pragma unroll
            for (int t = 7; t > 0; --t) {
                bool sw = (s[t] > s[t-1]) || (s[t] == s[t-1] && ix[t] < ix[t-1]);
                if (sw) {
                    float tv = s[t]; s[t] = s[t-1]; s[t-1] = tv;
                    int   ti = ix[t]; ix[t] = ix[t-1]; ix[t-1] = ti;
                }
            }
        }
    }
    #pragma unroll
    for (int i = 0; i < 8; ++i) { ls[tid * 8 + i] = s[i]; li[tid * 8 + i] = ix[i]; }
    __syncthreads();
    for (int w = 64; w >= 1; w >>= 2) {
        if (tid < w) {
            #pragma unroll
            for (int i = 0; i < 8; ++i) { s[i] = -1e30f; ix[i] = 0x7fffffff; }
            #pragma unroll
            for (int c = 0; c < 32; ++c) {
                float v  = ls[tid * 32 + c];
                int   vi = li[tid * 32 + c];
                bool better = (v > s[7]) || (v == s[7] && vi < ix[7]);
                if (better) {
                    s[7] = v; ix[7] = vi;
                    #pragma unroll
                    for (int t = 7; t > 0; --t) {
                        bool sw = (s[t] > s[t-1]) || (s[t] == s[t-1] && ix[t] < ix[t-1]);
                        if (sw) {
                            float tv = s[t]; s[t] = s[t-1]; s[t-1] = tv;
                            int   ti = ix[t]; ix[t] = ix[t-1]; ix[t-1] = ti;
                        }
                    }
                }
            }
        }
        __syncthreads();
        if (tid < w) {
            #pragma unroll
            for (int i = 0; i < 8; ++i) { ls[tid * 8 + i] = s[i]; li[tid * 8 + i] = ix[i]; }
        }
        __syncthreads();
    }
    if (tid < 8) {
        out_scores[(size_t)q * 8 + tid] = ls[tid];
        out_idx[q * 8 + tid]            = li[tid];
    }
}

// ---------------- gather retrieved docs ----------------
__global__ __launch_bounds__(256) void gather_kernel(const float* __restrict__ docs,
                                                     const int* __restrict__ idx,
                                                     float* __restrict__ out) {
    const int b = blockIdx.x;
    const int d = idx[b];
    const float4* src = (const float4*)(docs + (size_t)d * DTOK * EMB);
    float4*       dst = (float4*)(out + (size_t)b * DTOK * EMB);
    for (int i = threadIdx.x; i < DTOK * EMB / 4; i += 256) dst[i] = src[i];
}

extern "C" void kernel_launch(void* const* d_in, const int* in_sizes, int n_in,
                              void* d_out, int out_size, void* d_ws, size_t ws_size,
                              hipStream_t stream) {
    const float* qe   = (const float*)d_in[0];
    const float* de   = (const float*)d_in[1];
    const float* qW1  = (const float*)d_in[2];
    const float* qb1  = (const float*)d_in[3];
    const float* qW2  = (const float*)d_in[4];
    const float* qb2  = (const float*)d_in[5];
    const float* qg   = (const float*)d_in[6];
    const float* qbe  = (const float*)d_in[7];
    const float* dW1  = (const float*)d_in[8];
    const float* db1  = (const float*)d_in[9];
    const float* dW2  = (const float*)d_in[10];
    const float* db2  = (const float*)d_in[11];
    const float* dg   = (const float*)d_in[12];
    const float* dbe  = (const float*)d_in[13];
    const float* pW   = (const float*)d_in[14];
    const float* pb   = (const float*)d_in[15];
    const float* temp = (const float*)d_in[16];

    float* out = (float*)d_out;

    // ---- workspace carve (~510 MB) ----
    char* w = (char*)d_ws;
    float*  scores = (float*)w;                 w += (size_t)NQ * ND * 4;
    ushort* W1p    = (ushort*)w;                w += (size_t)HID * 3 * EMB * 2;
    ushort* W2p    = (ushort*)w;                w += (size_t)HID * 3 * HID * 2;
    ushort* pWp    = (ushort*)w;                w += (size_t)HID * 3 * HID * 2;
    ushort* QW1p   = (ushort*)w;                w += (size_t)HID * 3 * EMB * 2;
    ushort* QW2p   = (ushort*)w;                w += (size_t)HID * 3 * HID * 2;
    ushort* qpool  = (ushort*)w;                w += (size_t)NQ * 3 * EMB * 2;
    ushort* qh1a   = (ushort*)w;                w += (size_t)NQ * 3 * HID * 2;
    ushort* qlna   = (ushort*)w;                w += (size_t)NQ * 3 * HID * 2;
    ushort* qaug   = (ushort*)w;                w += (size_t)NQ * 3 * HID * 2;
    int*    tidx   = (int*)w;                   w += 4096;
    ushort* pooled = (ushort*)w;                w += (size_t)ND * 3 * EMB * 2;      // 230.4 MB
    ushort* h1a    = (ushort*)w;                w += (size_t)ND * 3 * HID * 2;      // 153.6 MB
    float*  h2     = (float*)w;                 w += (size_t)ND * HID * 4;          // 102.4 MB
    ushort* lna    = pooled;   // LN-aug overwrites pooled (dead after GEMM1)
    float*  pproj  = h2;       // GEMM3 out overwrites h2 (dead after ln_aug)
    ushort* Daug   = h1a;      // l2_augB overwrites h1a (dead after GEMM2)

    const int NPAN = (ND + 127) / 128;   // 391 row panels
    const int NWG  = NPAN * 2;           // 782 blocks (2 col panels each)

    // ---- weight conversion (tiny) ----
    wconv<<<HID, 256, 0, stream>>>(dW1, W1p, EMB);
    wconv<<<HID, 256, 0, stream>>>(dW2, W2p, HID);
    wconv<<<HID, 256, 0, stream>>>(pW,  pWp, HID);
    wconv<<<HID, 256, 0, stream>>>(qW1, QW1p, EMB);
    wconv<<<HID, 256, 0, stream>>>(qW2, QW2p, HID);

    // ---- query path (MFMA, fused epilogues, 4 launches) ----
    pool_aug<<<NQ, 192, 0, stream>>>(qe, qpool, QTOK);
    gemmF<0><<<1, 512, 0, stream>>>(qpool, QW1p, qb1, nullptr, nullptr, qh1a, NQ, 3 * EMB);
    gemmF<1><<<1, 512, 0, stream>>>(qh1a, QW2p, qb2, qg, qbe, qlna, NQ, 3 * HID);
    gemmF<2><<<1, 512, 0, stream>>>(qlna, pWp, pb, nullptr, nullptr, qaug, NQ, 3 * HID);

    // ---- doc path, full-M single pass, XCD-paired grids ----
    pool_aug<<<ND, 192, 0, stream>>>(de, pooled, DTOK);
    mfma_gemm2<1><<<NWG, 512, 0, stream>>>(pooled, W1p, db1, h1a, ND, 3 * EMB);
    mfma_gemm2<0><<<NWG, 512, 0, stream>>>(h1a, W2p, db2, h2, ND, 3 * HID);
    ln_aug<<<(ND + 3) / 4, 256, 0, stream>>>(h2, dg, dbe, lna, ND);
    mfma_gemm2<0><<<NWG, 512, 0, stream>>>(lna, pWp, pb, pproj, ND, 3 * HID);
    l2_augB<<<(ND + 3) / 4, 256, 0, stream>>>(pproj, Daug, ND);

    // ---- scores: [64, ND] = qaug x Daug^T * (1/T) ----
    mfma_scores<<<dim3(1, (ND + 255) / 256), 512, 0, stream>>>(qaug, Daug, scores,
                                                               NQ, ND, 3 * HID, (long)ND, temp);

    // ---- top-k + gather ----
    topk_kernel<<<NQ, 256, 0, stream>>>(scores, out, tidx, ND);
    gather_kernel<<<NQ * 8, 256, 0, stream>>>(de, tidx, out + NQ * 8);
}

// Round 7
// 1452.308 us; speedup vs baseline: 1.1678x; 1.1046x over previous
//
#include <hip/hip_runtime.h>

#define NQ 64
#define ND 50000
#define QTOK 32
#define DTOK 16
#define EMB 768
#define HID 512

typedef short s16x8 __attribute__((ext_vector_type(8)));
typedef float f32x4 __attribute__((ext_vector_type(4)));

// ---------- bf16 helpers (RNE) ----------
__device__ __forceinline__ unsigned short f2bf(float f) {
    union { float f; unsigned u; } x; x.f = f;
    unsigned r = x.u + 0x7fffu + ((x.u >> 16) & 1u);
    return (unsigned short)(r >> 16);
}
__device__ __forceinline__ float bf2f(unsigned short h) {
    union { unsigned u; float f; } x; x.u = ((unsigned)h) << 16;
    return x.f;
}
// pack two floats' hi parts into one uint; and lo parts
__device__ __forceinline__ unsigned packhi2(float a, float b) {
    return (unsigned)f2bf(a) | ((unsigned)f2bf(b) << 16);
}
__device__ __forceinline__ unsigned packlo2(float a, float b) {
    unsigned short ha = f2bf(a), hb = f2bf(b);
    return (unsigned)f2bf(a - bf2f(ha)) | ((unsigned)f2bf(b - bf2f(hb)) << 16);
}

__device__ __forceinline__ void gload_lds16(const void* g, void* l) {
    __builtin_amdgcn_global_load_lds(
        (const __attribute__((address_space(1))) void*)g,
        (__attribute__((address_space(3))) void*)l, 16, 0, 0);
}

// ============ storage layout ============
// All augmented tensors are [rows][2K] = [hi(0..K-1) | lo(0..K-1)] bf16.
// Logical GEMM K2 = 3K in regions [hiA*hiB | loA*hiB | hiA*loB]:
//   A k-offset: ka = k0 < 2K ? k0 : k0-2K
//   B k-offset: kb = k0 <  K ? k0 : k0-K

// ---------------- fp32 mean-pool (query path) ----------------
__global__ void pool_kernel(const float* __restrict__ in, float* __restrict__ out, int T) {
    int r = blockIdx.x;
    int t = threadIdx.x;  // 0..191
    const float4* ip = (const float4*)in + (size_t)r * T * (EMB / 4);
    float4 acc = make_float4(0.f, 0.f, 0.f, 0.f);
    for (int i = 0; i < T; ++i) {
        float4 v = ip[(size_t)i * (EMB / 4) + t];
        acc.x += v.x; acc.y += v.y; acc.z += v.z; acc.w += v.w;
    }
    float s = 1.0f / (float)T;
    acc.x *= s; acc.y *= s; acc.z *= s; acc.w *= s;
    ((float4*)out)[(size_t)r * (EMB / 4) + t] = acc;
}

// ---------------- doc mean-pool -> [hi(768)|lo(768)] bf16 ----------------
__global__ void pool_aug(const float* __restrict__ in, ushort* __restrict__ out) {
    int r = blockIdx.x, t = threadIdx.x;  // 192 threads x 4 floats
    const float4* ip = (const float4*)in + (size_t)r * DTOK * (EMB / 4) + t;
    float4 a = make_float4(0.f, 0.f, 0.f, 0.f);
    #pragma unroll
    for (int i = 0; i < DTOK; ++i) {
        float4 v = ip[(size_t)i * (EMB / 4)];
        a.x += v.x; a.y += v.y; a.z += v.z; a.w += v.w;
    }
    const float s = 1.0f / (float)DTOK;
    float v0 = a.x * s, v1 = a.y * s, v2 = a.z * s, v3 = a.w * s;
    ushort* base = out + (size_t)r * (2 * EMB);
    *(uint2*)(base + t * 4)       = make_uint2(packhi2(v0, v1), packhi2(v2, v3));
    *(uint2*)(base + EMB + t * 4) = make_uint2(packlo2(v0, v1), packlo2(v2, v3));
}

// ---------------- weight convert: W[K][512] fp32 -> Wp[512][2K] = [hi|lo] ----------------
__global__ void wconv(const float* __restrict__ W, ushort* __restrict__ Wp, int K) {
    int n = blockIdx.x;  // 512 blocks
    ushort* base = Wp + (size_t)n * 2 * K;
    for (int k = threadIdx.x; k < K; k += blockDim.x) {
        float v = W[(size_t)k * HID + n];
        unsigned short hi = f2bf(v);
        base[k]     = hi;
        base[K + k] = f2bf(v - bf2f(hi));
    }
}

// ---------------- doc MFMA GEMM: 128x256 tile, 8 waves, 2-D grid (round-3 proven) ----------------
// A [M][2K] A-layout, B [512][2K] B-layout. Logical K2 = 3K.
// MODE 0: fp32 out[M][HID] = acc + bias
// MODE 1: relu(acc+bias) -> [hi(512)|lo(512)] out[M][2*HID]
template <int MODE>
__global__ __launch_bounds__(512) void mfma_gemm2(const ushort* __restrict__ A,
                                                  const ushort* __restrict__ B,
                                                  const float* __restrict__ bias,
                                                  void* __restrict__ out,
                                                  int M, int K) {
    __shared__ ushort As[128 * 64];  // 16KB
    __shared__ ushort Bs[256 * 64];  // 32KB (48KB total -> 2+ blocks/CU)
    const int Ks = 2 * K;            // storage stride
    const int bm = blockIdx.x * 128;
    const int bn = blockIdx.y * 256;
    const int tid = threadIdx.x;
    const int lane = tid & 63;
    const int wave = tid >> 6;
    const int wr = wave >> 2;        // 0..1 : 64-row panel
    const int wc = wave & 3;         // 0..3 : 64-col panel
    f32x4 acc[4][4] = {};

    for (int k0 = 0; k0 < 3 * K; k0 += 64) {
        const int ka = (k0 < 2 * K) ? k0 : k0 - 2 * K;
        const int kb = (k0 < K) ? k0 : k0 - K;
        #pragma unroll
        for (int c = 0; c < 2; ++c) {   // stage A: 16KB
            int idx = c * 512 + tid;
            int row = idx >> 3, s = idx & 7;
            int gr = bm + row; if (gr >= M) gr = M - 1;
            int ks = (s ^ (row & 7)) << 3;
            gload_lds16(A + (size_t)gr * Ks + ka + ks, As + idx * 8);
        }
        #pragma unroll
        for (int c = 0; c < 4; ++c) {   // stage B: 32KB (bn+n <= 511 always valid)
            int idx = c * 512 + tid;
            int n = idx >> 3, s = idx & 7;
            int ks = (s ^ (n & 7)) << 3;
            gload_lds16(B + (size_t)(bn + n) * Ks + kb + ks, Bs + idx * 8);
        }
        __syncthreads();

        #pragma unroll
        for (int kk = 0; kk < 2; ++kk) {
            const int sp = kk * 4 + (lane >> 4);
            s16x8 a[4], b[4];
            #pragma unroll
            for (int i = 0; i < 4; ++i) {
                int r = wr * 64 + i * 16 + (lane & 15);
                a[i] = *(const s16x8*)(As + r * 64 + ((sp ^ (r & 7)) << 3));
            }
            #pragma unroll
            for (int j = 0; j < 4; ++j) {
                int n = wc * 64 + j * 16 + (lane & 15);
                b[j] = *(const s16x8*)(Bs + n * 64 + ((sp ^ (n & 7)) << 3));
            }
            #pragma unroll
            for (int i = 0; i < 4; ++i)
                #pragma unroll
                for (int j = 0; j < 4; ++j)
                    acc[i][j] = __builtin_amdgcn_mfma_f32_16x16x32_bf16(a[i], b[j], acc[i][j], 0, 0, 0);
        }
        __syncthreads();
    }

    // epilogue: C/D layout col=lane&15, row=(lane>>4)*4+reg
    #pragma unroll
    for (int j = 0; j < 4; ++j) {
        int col = bn + wc * 64 + j * 16 + (lane & 15);   // < 512
        float bv = bias[col];
        #pragma unroll
        for (int i = 0; i < 4; ++i) {
            #pragma unroll
            for (int r = 0; r < 4; ++r) {
                int grow = bm + wr * 64 + i * 16 + ((lane >> 4) << 2) + r;
                if (grow >= M) continue;
                float v = acc[i][j][r] + bv;
                if (MODE == 1) {
                    v = fmaxf(v, 0.0f);
                    unsigned short hi = f2bf(v);
                    ushort* op = (ushort*)out + (size_t)grow * (2 * HID);
                    op[col]       = hi;
                    op[HID + col] = f2bf(v - bf2f(hi));
                } else {
                    ((float*)out)[(size_t)grow * HID + col] = v;
                }
            }
        }
    }
}

// ---------------- scores MFMA GEMM: A [64][2K] A-layout, B [ND][2K] B-layout ----------------
__global__ __launch_bounds__(512) void mfma_scores(const ushort* __restrict__ A,
                                                   const ushort* __restrict__ B,
                                                   float* __restrict__ out,
                                                   int M, int N_B, int K, long ldo,
                                                   const float* __restrict__ temp) {
    __shared__ ushort As[128 * 64];
    __shared__ ushort Bs[256 * 64];
    const int Ks = 2 * K;
    const int bm = blockIdx.x * 128;
    const int bn = blockIdx.y * 256;
    const int tid = threadIdx.x;
    const int lane = tid & 63;
    const int wave = tid >> 6;
    const int wr = wave >> 2;
    const int wc = wave & 3;
    f32x4 acc[4][4] = {};

    for (int k0 = 0; k0 < 3 * K; k0 += 64) {
        const int ka = (k0 < 2 * K) ? k0 : k0 - 2 * K;
        const int kb = (k0 < K) ? k0 : k0 - K;
        #pragma unroll
        for (int c = 0; c < 2; ++c) {
            int idx = c * 512 + tid;
            int row = idx >> 3, s = idx & 7;
            int gr = bm + row; if (gr >= M) gr = M - 1;
            int ks = (s ^ (row & 7)) << 3;
            gload_lds16(A + (size_t)gr * Ks + ka + ks, As + idx * 8);
        }
        #pragma unroll
        for (int c = 0; c < 4; ++c) {
            int idx = c * 512 + tid;
            int n = idx >> 3, s = idx & 7;
            int gn = bn + n; if (gn >= N_B) gn = N_B - 1;
            int ks = (s ^ (n & 7)) << 3;
            gload_lds16(B + (size_t)gn * Ks + kb + ks, Bs + idx * 8);
        }
        __syncthreads();

        #pragma unroll
        for (int kk = 0; kk < 2; ++kk) {
            const int sp = kk * 4 + (lane >> 4);
            s16x8 a[4], b[4];
            #pragma unroll
            for (int i = 0; i < 4; ++i) {
                int r = wr * 64 + i * 16 + (lane & 15);
                a[i] = *(const s16x8*)(As + r * 64 + ((sp ^ (r & 7)) << 3));
            }
            #pragma unroll
            for (int j = 0; j < 4; ++j) {
                int n = wc * 64 + j * 16 + (lane & 15);
                b[j] = *(const s16x8*)(Bs + n * 64 + ((sp ^ (n & 7)) << 3));
            }
            #pragma unroll
            for (int i = 0; i < 4; ++i)
                #pragma unroll
                for (int j = 0; j < 4; ++j)
                    acc[i][j] = __builtin_amdgcn_mfma_f32_16x16x32_bf16(a[i], b[j], acc[i][j], 0, 0, 0);
        }
        __syncthreads();
    }

    float invT = 1.0f / temp[0];
    #pragma unroll
    for (int j = 0; j < 4; ++j) {
        int gcol = bn + wc * 64 + j * 16 + (lane & 15);
        #pragma unroll
        for (int i = 0; i < 4; ++i)
            #pragma unroll
            for (int r = 0; r < 4; ++r) {
                int grow = bm + wr * 64 + i * 16 + ((lane >> 4) << 2) + r;
                if (grow < M && gcol < N_B)
                    out[(size_t)grow * ldo + gcol] = acc[i][j][r] * invT;
            }
    }
}

// ---------------- in-place fp32 LayerNorm (query path) ----------------
__global__ __launch_bounds__(256) void ln_kernel(float* __restrict__ x,
                                                 const float* __restrict__ g,
                                                 const float* __restrict__ be, int M) {
    int wv = threadIdx.x >> 6, lane = threadIdx.x & 63;
    int row = blockIdx.x * 4 + wv;
    if (row >= M) return;
    float4* p = (float4*)(x + (size_t)row * HID);
    float4 a = p[lane * 2], b = p[lane * 2 + 1];
    float s  = a.x + a.y + a.z + a.w + b.x + b.y + b.z + b.w;
    float sq = a.x*a.x + a.y*a.y + a.z*a.z + a.w*a.w
             + b.x*b.x + b.y*b.y + b.z*b.z + b.w*b.w;
    #pragma unroll
    for (int o = 32; o > 0; o >>= 1) { s += __shfl_xor(s, o); sq += __shfl_xor(sq, o); }
    float mu  = s * (1.0f / HID);
    float var = sq * (1.0f / HID) - mu * mu;
    float r   = rsqrtf(var + 1e-5f);
    const float4* gp = (const float4*)g;
    const float4* bp = (const float4*)be;
    float4 g0 = gp[lane * 2], g1 = gp[lane * 2 + 1];
    float4 b0 = bp[lane * 2], b1 = bp[lane * 2 + 1];
    a.x = (a.x - mu) * r * g0.x + b0.x;  a.y = (a.y - mu) * r * g0.y + b0.y;
    a.z = (a.z - mu) * r * g0.z + b0.z;  a.w = (a.w - mu) * r * g0.w + b0.w;
    b.x = (b.x - mu) * r * g1.x + b1.x;  b.y = (b.y - mu) * r * g1.y + b1.y;
    b.z = (b.z - mu) * r * g1.z + b1.z;  b.w = (b.w - mu) * r * g1.w + b1.w;
    p[lane * 2] = a; p[lane * 2 + 1] = b;
}

// ---------------- shared hi|lo writer: 8 consecutive cols per lane ----------------
__device__ __forceinline__ void store_hilo(ushort* __restrict__ base, int lane,
                                           float v0, float v1, float v2, float v3,
                                           float v4, float v5, float v6, float v7) {
    *(uint4*)(base + lane * 8) =
        make_uint4(packhi2(v0, v1), packhi2(v2, v3), packhi2(v4, v5), packhi2(v6, v7));
    *(uint4*)(base + HID + lane * 8) =
        make_uint4(packlo2(v0, v1), packlo2(v2, v3), packlo2(v4, v5), packlo2(v6, v7));
}

// ---------------- LayerNorm fp32 -> [hi|lo] bf16 [M][2*HID] (doc path) ----------------
__global__ __launch_bounds__(256) void ln_aug(const float* __restrict__ x,
                                              const float* __restrict__ g,
                                              const float* __restrict__ be,
                                              ushort* __restrict__ out, int M) {
    int wv = threadIdx.x >> 6, lane = threadIdx.x & 63;
    int row = blockIdx.x * 4 + wv;
    if (row >= M) return;
    const float4* p = (const float4*)(x + (size_t)row * HID);
    float4 a = p[lane * 2], b = p[lane * 2 + 1];
    float s  = a.x + a.y + a.z + a.w + b.x + b.y + b.z + b.w;
    float sq = a.x*a.x + a.y*a.y + a.z*a.z + a.w*a.w
             + b.x*b.x + b.y*b.y + b.z*b.z + b.w*b.w;
    #pragma unroll
    for (int o = 32; o > 0; o >>= 1) { s += __shfl_xor(s, o); sq += __shfl_xor(sq, o); }
    float mu  = s * (1.0f / HID);
    float var = sq * (1.0f / HID) - mu * mu;
    float r   = rsqrtf(var + 1e-5f);
    const float4* gp = (const float4*)g;
    const float4* bp = (const float4*)be;
    float4 g0 = gp[lane * 2], g1 = gp[lane * 2 + 1];
    float4 b0 = bp[lane * 2], b1 = bp[lane * 2 + 1];
    store_hilo(out + (size_t)row * (2 * HID), lane,
               (a.x - mu) * r * g0.x + b0.x, (a.y - mu) * r * g0.y + b0.y,
               (a.z - mu) * r * g0.z + b0.z, (a.w - mu) * r * g0.w + b0.w,
               (b.x - mu) * r * g1.x + b1.x, (b.y - mu) * r * g1.y + b1.y,
               (b.z - mu) * r * g1.z + b1.z, (b.w - mu) * r * g1.w + b1.w);
}

// ---------------- L2-normalize fp32 -> [hi|lo] bf16 [M][2*HID] (doc path) ----------------
__global__ __launch_bounds__(256) void l2_aug(const float* __restrict__ x,
                                              ushort* __restrict__ out, int M) {
    int wv = threadIdx.x >> 6, lane = threadIdx.x & 63;
    int row = blockIdx.x * 4 + wv;
    if (row >= M) return;
    const float4* p = (const float4*)(x + (size_t)row * HID);
    float4 a = p[lane * 2], b = p[lane * 2 + 1];
    float sq = a.x*a.x + a.y*a.y + a.z*a.z + a.w*a.w
             + b.x*b.x + b.y*b.y + b.z*b.z + b.w*b.w;
    #pragma unroll
    for (int o = 32; o > 0; o >>= 1) sq += __shfl_xor(sq, o);
    float n = sqrtf(sq);
    float r = 1.0f / fmaxf(n, 1e-12f);
    store_hilo(out + (size_t)row * (2 * HID), lane,
               a.x * r, a.y * r, a.z * r, a.w * r,
               b.x * r, b.y * r, b.z * r, b.w * r);
}

// ---------------- in-place L2 normalize (query path fp32) ----------------
__global__ __launch_bounds__(256) void l2_kernel(float* __restrict__ x, int M) {
    int wv = threadIdx.x >> 6, lane = threadIdx.x & 63;
    int row = blockIdx.x * 4 + wv;
    if (row >= M) return;
    float4* p = (float4*)(x + (size_t)row * HID);
    float4 a = p[lane * 2], b = p[lane * 2 + 1];
    float sq = a.x*a.x + a.y*a.y + a.z*a.z + a.w*a.w
             + b.x*b.x + b.y*b.y + b.z*b.z + b.w*b.w;
    #pragma unroll
    for (int o = 32; o > 0; o >>= 1) sq += __shfl_xor(sq, o);
    float n = sqrtf(sq);
    float r = 1.0f / fmaxf(n, 1e-12f);
    a.x *= r; a.y *= r; a.z *= r; a.w *= r;
    b.x *= r; b.y *= r; b.z *= r; b.w *= r;
    p[lane * 2] = a; p[lane * 2 + 1] = b;
}

// ---------------- fp32 -> [hi|lo] (queries) ----------------
__global__ __launch_bounds__(256) void fp32_aug(const float* __restrict__ x,
                                                ushort* __restrict__ out, int M) {
    int wv = threadIdx.x >> 6, lane = threadIdx.x & 63;
    int row = blockIdx.x * 4 + wv;
    if (row >= M) return;
    const float4* p = (const float4*)(x + (size_t)row * HID);
    float4 a = p[lane * 2], b = p[lane * 2 + 1];
    store_hilo(out + (size_t)row * (2 * HID), lane,
               a.x, a.y, a.z, a.w, b.x, b.y, b.z, b.w);
}

// ---------------- fp32 GEMM for the tiny query path ----------------
template <int RELU>
__global__ __launch_bounds__(256) void gemm_nn(const float* __restrict__ A,
                                               const float* __restrict__ W,
                                               const float* __restrict__ bias,
                                               float* __restrict__ C,
                                               int M, int K, int N) {
    __shared__ float As[16][68];
    __shared__ float Bs[16][64];
    const int bm = blockIdx.x * 64;
    const int bn = blockIdx.y * 64;
    const int tid = threadIdx.x;
    const int tx = tid & 15, ty = tid >> 4;
    float acc[4][4] = {};
    for (int k0 = 0; k0 < K; k0 += 16) {
        {
            int row = tid >> 2;
            int kk  = (tid & 3) << 2;
            int gr  = bm + row;
            float4 v = make_float4(0.f, 0.f, 0.f, 0.f);
            if (gr < M) v = *(const float4*)(A + (size_t)gr * K + k0 + kk);
            As[kk + 0][row] = v.x; As[kk + 1][row] = v.y;
            As[kk + 2][row] = v.z; As[kk + 3][row] = v.w;
        }
        {
            int n  = tid & 63;
            int kb = tid >> 6;
            #pragma unroll
            for (int q = 0; q < 4; ++q) {
                int kr = kb + q * 4;
                Bs[kr][n] = W[(size_t)(k0 + kr) * N + bn + n];
            }
        }
        __syncthreads();
        #pragma unroll
        for (int k = 0; k < 16; ++k) {
            float4 av = *(const float4*)&As[k][ty << 2];
            float4 bv = *(const float4*)&Bs[k][tx << 2];
            float a[4] = {av.x, av.y, av.z, av.w};
            float b[4] = {bv.x, bv.y, bv.z, bv.w};
            #pragma unroll
            for (int i = 0; i < 4; ++i)
                #pragma unroll
                for (int j = 0; j < 4; ++j)
                    acc[i][j] = fmaf(a[i], b[j], acc[i][j]);
        }
        __syncthreads();
    }
    #pragma unroll
    for (int i = 0; i < 4; ++i) {
        int gr = bm + (ty << 2) + i;
        if (gr >= M) continue;
        #pragma unroll
        for (int j = 0; j < 4; ++j) {
            int gc = bn + (tx << 2) + j;
            float v = acc[i][j] + bias[gc];
            if (RELU) v = fmaxf(v, 0.0f);
            C[(size_t)gr * N + gc] = v;
        }
    }
}

// ---------------- top-8 per row with lowest-index tie-break ----------------
__global__ __launch_bounds__(256) void topk_kernel(const float* __restrict__ scores,
                                                   float* __restrict__ out_scores,
                                                   int* __restrict__ out_idx, int N) {
    __shared__ float ls[2048];
    __shared__ int   li[2048];
    const int q   = blockIdx.x;
    const int tid = threadIdx.x;
    const float* row = scores + (size_t)q * N;
    float s[8]; int ix[8];
    #pragma unroll
    for (int i = 0; i < 8; ++i) { s[i] = -1e30f; ix[i] = 0x7fffffff; }
    for (int j = tid; j < N; j += 256) {
        float v = row[j];
        if (v > s[7]) {
            s[7] = v; ix[7] = j;
            #pragma unroll
            for (int t = 7; t > 0; --t) {
                bool sw = (s[t] > s[t-1]) || (s[t] == s[t-1] && ix[t] < ix[t-1]);
                if (sw) {
                    float tv = s[t]; s[t] = s[t-1]; s[t-1] = tv;
                    int   ti = ix[t]; ix[t] = ix[t-1]; ix[t-1] = ti;
                }
            }
        }
    }
    #pragma unroll
    for (int i = 0; i < 8; ++i) { ls[tid * 8 + i] = s[i]; li[tid * 8 + i] = ix[i]; }
    __syncthreads();
    for (int w = 64; w >= 1; w >>= 2) {
        if (tid < w) {
            #pragma unroll
            for (int i = 0; i < 8; ++i) { s[i] = -1e30f; ix[i] = 0x7fffffff; }
            #pragma unroll
            for (int c = 0; c < 32; ++c) {
                float v  = ls[tid * 32 + c];
                int   vi = li[tid * 32 + c];
                bool better = (v > s[7]) || (v == s[7] && vi < ix[7]);
                if (better) {
                    s[7] = v; ix[7] = vi;
                    #pragma unroll
                    for (int t = 7; t > 0; --t) {
                        bool sw = (s[t] > s[t-1]) || (s[t] == s[t-1] && ix[t] < ix[t-1]);
                        if (sw) {
                            float tv = s[t]; s[t] = s[t-1]; s[t-1] = tv;
                            int   ti = ix[t]; ix[t] = ix[t-1]; ix[t-1] = ti;
                        }
                    }
                }
            }
        }
        __syncthreads();
        if (tid < w) {
            #pragma unroll
            for (int i = 0; i < 8; ++i) { ls[tid * 8 + i] = s[i]; li[tid * 8 + i] = ix[i]; }
        }
        __syncthreads();
    }
    if (tid < 8) {
        out_scores[(size_t)q * 8 + tid] = ls[tid];
        out_idx[q * 8 + tid]            = li[tid];
    }
}

// ---------------- gather retrieved docs ----------------
__global__ __launch_bounds__(256) void gather_kernel(const float* __restrict__ docs,
                                                     const int* __restrict__ idx,
                                                     float* __restrict__ out) {
    const int b = blockIdx.x;
    const int d = idx[b];
    const float4* src = (const float4*)(docs + (size_t)d * DTOK * EMB);
    float4*       dst = (float4*)(out + (size_t)b * DTOK * EMB);
    for (int i = threadIdx.x; i < DTOK * EMB / 4; i += 256) dst[i] = src[i];
}

extern "C" void kernel_launch(void* const* d_in, const int* in_sizes, int n_in,
                              void* d_out, int out_size, void* d_ws, size_t ws_size,
                              hipStream_t stream) {
    const float* qe   = (const float*)d_in[0];
    const float* de   = (const float*)d_in[1];
    const float* qW1  = (const float*)d_in[2];
    const float* qb1  = (const float*)d_in[3];
    const float* qW2  = (const float*)d_in[4];
    const float* qb2  = (const float*)d_in[5];
    const float* qg   = (const float*)d_in[6];
    const float* qbe  = (const float*)d_in[7];
    const float* dW1  = (const float*)d_in[8];
    const float* db1  = (const float*)d_in[9];
    const float* dW2  = (const float*)d_in[10];
    const float* db2  = (const float*)d_in[11];
    const float* dg   = (const float*)d_in[12];
    const float* dbe  = (const float*)d_in[13];
    const float* pW   = (const float*)d_in[14];
    const float* pb   = (const float*)d_in[15];
    const float* temp = (const float*)d_in[16];

    float* out = (float*)d_out;

    // ---- workspace carve (~375 MB) ----
    char* w = (char*)d_ws;
    float*  scores = (float*)w;                 w += (size_t)NQ * ND * 4;
    ushort* W1p    = (ushort*)w;                w += (size_t)HID * 2 * EMB * 2;     // 1.57 MB
    ushort* W2p    = (ushort*)w;                w += (size_t)HID * 2 * HID * 2;     // 1.05 MB
    ushort* pWp    = (ushort*)w;                w += (size_t)HID * 2 * HID * 2;     // 1.05 MB
    float*  qpool  = (float*)w;                 w += (size_t)NQ * EMB * 4;
    float*  qh1    = (float*)w;                 w += (size_t)NQ * HID * 4;
    float*  qh2    = (float*)w;                 w += (size_t)NQ * HID * 4;
    float*  qn     = (float*)w;                 w += (size_t)NQ * HID * 4;
    ushort* qaug   = (ushort*)w;                w += (size_t)NQ * 2 * HID * 2;
    int*    tidx   = (int*)w;                   w += 4096;
    ushort* pooled = (ushort*)w;                w += (size_t)ND * 2 * EMB * 2;      // 153.6 MB
    ushort* h1a    = (ushort*)w;                w += (size_t)ND * 2 * HID * 2;      // 102.4 MB
    float*  h2     = (float*)w;                 w += (size_t)ND * HID * 4;          // 102.4 MB
    ushort* lna    = pooled;   // LN-aug overwrites pooled (dead after GEMM1)
    float*  pproj  = h2;       // GEMM3 out overwrites h2 (dead after ln_aug)
    ushort* Daug   = h1a;      // l2_aug overwrites h1a (dead after GEMM2)

    const int GM = (ND + 127) / 128;   // 391 row panels

    // ---- weight conversion (tiny) ----
    wconv<<<HID, 256, 0, stream>>>(dW1, W1p, EMB);
    wconv<<<HID, 256, 0, stream>>>(dW2, W2p, HID);
    wconv<<<HID, 256, 0, stream>>>(pW,  pWp, HID);

    // ---- query path (fp32, tiny) ----
    pool_kernel<<<NQ, 192, 0, stream>>>(qe, qpool, QTOK);
    gemm_nn<1><<<dim3(1, 8), 256, 0, stream>>>(qpool, qW1, qb1, qh1, NQ, EMB, HID);
    gemm_nn<0><<<dim3(1, 8), 256, 0, stream>>>(qh1, qW2, qb2, qh2, NQ, HID, HID);
    ln_kernel<<<(NQ + 3) / 4, 256, 0, stream>>>(qh2, qg, qbe, NQ);
    gemm_nn<0><<<dim3(1, 8), 256, 0, stream>>>(qh2, pW, pb, qn, NQ, HID, HID);
    l2_kernel<<<(NQ + 3) / 4, 256, 0, stream>>>(qn, NQ);
    fp32_aug<<<(NQ + 3) / 4, 256, 0, stream>>>(qn, qaug, NQ);

    // ---- doc path, full-M single pass (round-3 grid) ----
    pool_aug<<<ND, 192, 0, stream>>>(de, pooled);
    mfma_gemm2<1><<<dim3(GM, 2), 512, 0, stream>>>(pooled, W1p, db1, h1a, ND, EMB);
    mfma_gemm2<0><<<dim3(GM, 2), 512, 0, stream>>>(h1a, W2p, db2, h2, ND, HID);
    ln_aug<<<(ND + 3) / 4, 256, 0, stream>>>(h2, dg, dbe, lna, ND);
    mfma_gemm2<0><<<dim3(GM, 2), 512, 0, stream>>>(lna, pWp, pb, pproj, ND, HID);
    l2_aug<<<(ND + 3) / 4, 256, 0, stream>>>(pproj, Daug, ND);

    // ---- scores: [64, ND] = qaug x Daug^T * (1/T) ----
    mfma_scores<<<dim3(1, (ND + 255) / 256), 512, 0, stream>>>(qaug, Daug, scores,
                                                               NQ, ND, HID, (long)ND, temp);

    // ---- top-k + gather ----
    topk_kernel<<<NQ, 256, 0, stream>>>(scores, out, tidx, ND);
    gather_kernel<<<NQ * 8, 256, 0, stream>>>(de, tidx, out + NQ * 8);
}

// Round 9
// 1353.272 us; speedup vs baseline: 1.2532x; 1.0732x over previous
//
#include <hip/hip_runtime.h>

#define NQ 64
#define ND 50000
#define NDP 50048              // padded doc rows (391 full 128-panels)
#define MT (NDP + NQ)          // 50112 total rows (docs + pad + queries)
#define QTOK 32
#define DTOK 16
#define EMB 768
#define HID 512

typedef short s16x8 __attribute__((ext_vector_type(8)));
typedef float f32x4 __attribute__((ext_vector_type(4)));

// ---------- bf16 helpers (RNE) ----------
__device__ __forceinline__ unsigned short f2bf(float f) {
    union { float f; unsigned u; } x; x.f = f;
    unsigned r = x.u + 0x7fffu + ((x.u >> 16) & 1u);
    return (unsigned short)(r >> 16);
}
__device__ __forceinline__ float bf2f(unsigned short h) {
    union { unsigned u; float f; } x; x.u = ((unsigned)h) << 16;
    return x.f;
}
__device__ __forceinline__ unsigned packhi2(float a, float b) {
    return (unsigned)f2bf(a) | ((unsigned)f2bf(b) << 16);
}
__device__ __forceinline__ unsigned packlo2(float a, float b) {
    unsigned short ha = f2bf(a), hb = f2bf(b);
    return (unsigned)f2bf(a - bf2f(ha)) | ((unsigned)f2bf(b - bf2f(hb)) << 16);
}

__device__ __forceinline__ void gload_lds16(const void* g, void* l) {
    __builtin_amdgcn_global_load_lds(
        (const __attribute__((address_space(1))) void*)g,
        (__attribute__((address_space(3))) void*)l, 16, 0, 0);
}

// ============ storage layout ============
// Augmented tensors: [rows][2K] = [hi(0..K-1) | lo(0..K-1)] bf16 (side-agnostic).
// Logical GEMM K2 = 3K in regions [hiA*hiB | loA*hiB | hiA*loB]:
//   A k-offset: ka = k0 < 2K ? k0 : k0-2K
//   B k-offset: kb = k0 <  K ? k0 : k0-K
// Rows 0..49999 docs, 50000..50047 pad (garbage, never consumed), 50048..50111 queries.

// ---------------- mean-pool (docs + queries) -> [hi|lo] bf16 [2*EMB] ----------------
__global__ void pool_aug_all(const float* __restrict__ de, const float* __restrict__ qe,
                             ushort* __restrict__ out) {
    int blk = blockIdx.x, t = threadIdx.x;  // 192 threads x 4 floats
    const float* src;
    int T;
    size_t orow;
    if (blk < ND) { src = de + (size_t)blk * DTOK * EMB; T = DTOK; orow = blk; }
    else          { int qr = blk - ND; src = qe + (size_t)qr * QTOK * EMB; T = QTOK; orow = NDP + qr; }
    const float4* ip = (const float4*)src + t;
    float4 a = make_float4(0.f, 0.f, 0.f, 0.f);
    for (int i = 0; i < T; ++i) {
        float4 v = ip[(size_t)i * (EMB / 4)];
        a.x += v.x; a.y += v.y; a.z += v.z; a.w += v.w;
    }
    const float s = 1.0f / (float)T;
    float v0 = a.x * s, v1 = a.y * s, v2 = a.z * s, v3 = a.w * s;
    ushort* base = out + orow * (2 * EMB);
    *(uint2*)(base + t * 4)       = make_uint2(packhi2(v0, v1), packhi2(v2, v3));
    *(uint2*)(base + EMB + t * 4) = make_uint2(packlo2(v0, v1), packlo2(v2, v3));
}

// ---------------- weight convert: W[K][512] fp32 -> Wp[512][2K] = [hi|lo] ----------------
__global__ void wconv(const float* __restrict__ W, ushort* __restrict__ Wp, int K) {
    int n = blockIdx.x;  // 512 blocks
    ushort* base = Wp + (size_t)n * 2 * K;
    for (int k = threadIdx.x; k < K; k += blockDim.x) {
        float v = W[(size_t)k * HID + n];
        unsigned short hi = f2bf(v);
        base[k]     = hi;
        base[K + k] = f2bf(v - bf2f(hi));
    }
}

// ---------------- MFMA GEMM: 128x256 tile, 8 waves, per-panel weight select ----------------
// A [MT][2K]; Bd/Bq [512][2K]. Blocks with bm >= NDP use Bq/biasq (query rows).
// MODE 0: fp32 out[MT][HID] = acc + bias
// MODE 1: relu(acc+bias) -> [hi(512)|lo(512)] out[MT][2*HID]
template <int MODE>
__global__ __launch_bounds__(512, 4) void mfma_gemm2(const ushort* __restrict__ A,
                                                     const ushort* __restrict__ Bd,
                                                     const ushort* __restrict__ Bq,
                                                     const float* __restrict__ biasd,
                                                     const float* __restrict__ biasq,
                                                     void* __restrict__ out,
                                                     int M, int K) {
    __shared__ ushort As[128 * 64];  // 16KB
    __shared__ ushort Bs[256 * 64];  // 32KB (48KB total)
    const int Ks = 2 * K;            // storage stride
    const int bm = blockIdx.x * 128;
    const int bn = blockIdx.y * 256;
    const bool isq = (bm >= NDP);
    const ushort* B = isq ? Bq : Bd;
    const float* bias = isq ? biasq : biasd;
    const int tid = threadIdx.x;
    const int lane = tid & 63;
    const int wave = tid >> 6;
    const int wr = wave >> 2;        // 0..1 : 64-row panel
    const int wc = wave & 3;         // 0..3 : 64-col panel
    f32x4 acc[4][4] = {};

    for (int k0 = 0; k0 < 3 * K; k0 += 64) {
        const int ka = (k0 < 2 * K) ? k0 : k0 - 2 * K;
        const int kb = (k0 < K) ? k0 : k0 - K;
        #pragma unroll
        for (int c = 0; c < 2; ++c) {   // stage A: 16KB
            int idx = c * 512 + tid;
            int row = idx >> 3, s = idx & 7;
            int gr = bm + row; if (gr >= M) gr = M - 1;
            int ks = (s ^ (row & 7)) << 3;
            gload_lds16(A + (size_t)gr * Ks + ka + ks, As + idx * 8);
        }
        #pragma unroll
        for (int c = 0; c < 4; ++c) {   // stage B: 32KB (bn+n <= 511 always valid)
            int idx = c * 512 + tid;
            int n = idx >> 3, s = idx & 7;
            int ks = (s ^ (n & 7)) << 3;
            gload_lds16(B + (size_t)(bn + n) * Ks + kb + ks, Bs + idx * 8);
        }
        __syncthreads();

        #pragma unroll
        for (int kk = 0; kk < 2; ++kk) {
            const int sp = kk * 4 + (lane >> 4);
            s16x8 a[4], b[4];
            #pragma unroll
            for (int i = 0; i < 4; ++i) {
                int r = wr * 64 + i * 16 + (lane & 15);
                a[i] = *(const s16x8*)(As + r * 64 + ((sp ^ (r & 7)) << 3));
            }
            #pragma unroll
            for (int j = 0; j < 4; ++j) {
                int n = wc * 64 + j * 16 + (lane & 15);
                b[j] = *(const s16x8*)(Bs + n * 64 + ((sp ^ (n & 7)) << 3));
            }
            #pragma unroll
            for (int i = 0; i < 4; ++i)
                #pragma unroll
                for (int j = 0; j < 4; ++j)
                    acc[i][j] = __builtin_amdgcn_mfma_f32_16x16x32_bf16(a[i], b[j], acc[i][j], 0, 0, 0);
        }
        __syncthreads();
    }

    // epilogue: C/D layout col=lane&15, row=(lane>>4)*4+reg
    #pragma unroll
    for (int j = 0; j < 4; ++j) {
        int col = bn + wc * 64 + j * 16 + (lane & 15);   // < 512
        float bv = bias[col];
        #pragma unroll
        for (int i = 0; i < 4; ++i) {
            #pragma unroll
            for (int r = 0; r < 4; ++r) {
                int grow = bm + wr * 64 + i * 16 + ((lane >> 4) << 2) + r;
                if (grow >= M) continue;
                float v = acc[i][j][r] + bv;
                if (MODE == 1) {
                    v = fmaxf(v, 0.0f);
                    unsigned short hi = f2bf(v);
                    ushort* op = (ushort*)out + (size_t)grow * (2 * HID);
                    op[col]       = hi;
                    op[HID + col] = f2bf(v - bf2f(hi));
                } else {
                    ((float*)out)[(size_t)grow * HID + col] = v;
                }
            }
        }
    }
}

// ---------------- scores MFMA GEMM: A [64][2K], B [ND][2K] ----------------
__global__ __launch_bounds__(512, 4) void mfma_scores(const ushort* __restrict__ A,
                                                      const ushort* __restrict__ B,
                                                      float* __restrict__ out,
                                                      int M, int N_B, int K, long ldo,
                                                      const float* __restrict__ temp) {
    __shared__ ushort As[128 * 64];
    __shared__ ushort Bs[256 * 64];
    const int Ks = 2 * K;
    const int bm = blockIdx.x * 128;
    const int bn = blockIdx.y * 256;
    const int tid = threadIdx.x;
    const int lane = tid & 63;
    const int wave = tid >> 6;
    const int wr = wave >> 2;
    const int wc = wave & 3;
    f32x4 acc[4][4] = {};

    for (int k0 = 0; k0 < 3 * K; k0 += 64) {
        const int ka = (k0 < 2 * K) ? k0 : k0 - 2 * K;
        const int kb = (k0 < K) ? k0 : k0 - K;
        #pragma unroll
        for (int c = 0; c < 2; ++c) {
            int idx = c * 512 + tid;
            int row = idx >> 3, s = idx & 7;
            int gr = bm + row; if (gr >= M) gr = M - 1;
            int ks = (s ^ (row & 7)) << 3;
            gload_lds16(A + (size_t)gr * Ks + ka + ks, As + idx * 8);
        }
        #pragma unroll
        for (int c = 0; c < 4; ++c) {
            int idx = c * 512 + tid;
            int n = idx >> 3, s = idx & 7;
            int gn = bn + n; if (gn >= N_B) gn = N_B - 1;
            int ks = (s ^ (n & 7)) << 3;
            gload_lds16(B + (size_t)gn * Ks + kb + ks, Bs + idx * 8);
        }
        __syncthreads();

        #pragma unroll
        for (int kk = 0; kk < 2; ++kk) {
            const int sp = kk * 4 + (lane >> 4);
            s16x8 a[4], b[4];
            #pragma unroll
            for (int i = 0; i < 4; ++i) {
                int r = wr * 64 + i * 16 + (lane & 15);
                a[i] = *(const s16x8*)(As + r * 64 + ((sp ^ (r & 7)) << 3));
            }
            #pragma unroll
            for (int j = 0; j < 4; ++j) {
                int n = wc * 64 + j * 16 + (lane & 15);
                b[j] = *(const s16x8*)(Bs + n * 64 + ((sp ^ (n & 7)) << 3));
            }
            #pragma unroll
            for (int i = 0; i < 4; ++i)
                #pragma unroll
                for (int j = 0; j < 4; ++j)
                    acc[i][j] = __builtin_amdgcn_mfma_f32_16x16x32_bf16(a[i], b[j], acc[i][j], 0, 0, 0);
        }
        __syncthreads();
    }

    float invT = 1.0f / temp[0];
    #pragma unroll
    for (int j = 0; j < 4; ++j) {
        int gcol = bn + wc * 64 + j * 16 + (lane & 15);
        #pragma unroll
        for (int i = 0; i < 4; ++i)
            #pragma unroll
            for (int r = 0; r < 4; ++r) {
                int grow = bm + wr * 64 + i * 16 + ((lane >> 4) << 2) + r;
                if (grow < M && gcol < N_B)
                    out[(size_t)grow * ldo + gcol] = acc[i][j][r] * invT;
            }
    }
}

// ---------------- shared hi|lo writer: 8 consecutive cols per lane ----------------
__device__ __forceinline__ void store_hilo(ushort* __restrict__ base, int lane,
                                           float v0, float v1, float v2, float v3,
                                           float v4, float v5, float v6, float v7) {
    *(uint4*)(base + lane * 8) =
        make_uint4(packhi2(v0, v1), packhi2(v2, v3), packhi2(v4, v5), packhi2(v6, v7));
    *(uint4*)(base + HID + lane * 8) =
        make_uint4(packlo2(v0, v1), packlo2(v2, v3), packlo2(v4, v5), packlo2(v6, v7));
}

// ---------------- LayerNorm fp32 -> [hi|lo] bf16 [2*HID]; per-row param select ----------------
__global__ __launch_bounds__(256) void ln_aug(const float* __restrict__ x,
                                              const float* __restrict__ dg,
                                              const float* __restrict__ dbe,
                                              const float* __restrict__ qg,
                                              const float* __restrict__ qbe,
                                              ushort* __restrict__ out, int M) {
    int wv = threadIdx.x >> 6, lane = threadIdx.x & 63;
    int row = blockIdx.x * 4 + wv;
    if (row >= M) return;
    const float* g  = (row >= NDP) ? qg  : dg;
    const float* be = (row >= NDP) ? qbe : dbe;
    const float4* p = (const float4*)(x + (size_t)row * HID);
    float4 a = p[lane * 2], b = p[lane * 2 + 1];
    float s  = a.x + a.y + a.z + a.w + b.x + b.y + b.z + b.w;
    float sq = a.x*a.x + a.y*a.y + a.z*a.z + a.w*a.w
             + b.x*b.x + b.y*b.y + b.z*b.z + b.w*b.w;
    #pragma unroll
    for (int o = 32; o > 0; o >>= 1) { s += __shfl_xor(s, o); sq += __shfl_xor(sq, o); }
    float mu  = s * (1.0f / HID);
    float var = sq * (1.0f / HID) - mu * mu;
    float r   = rsqrtf(var + 1e-5f);
    const float4* gp = (const float4*)g;
    const float4* bp = (const float4*)be;
    float4 g0 = gp[lane * 2], g1 = gp[lane * 2 + 1];
    float4 b0 = bp[lane * 2], b1 = bp[lane * 2 + 1];
    store_hilo(out + (size_t)row * (2 * HID), lane,
               (a.x - mu) * r * g0.x + b0.x, (a.y - mu) * r * g0.y + b0.y,
               (a.z - mu) * r * g0.z + b0.z, (a.w - mu) * r * g0.w + b0.w,
               (b.x - mu) * r * g1.x + b1.x, (b.y - mu) * r * g1.y + b1.y,
               (b.z - mu) * r * g1.z + b1.z, (b.w - mu) * r * g1.w + b1.w);
}

// ---------------- L2-normalize fp32 -> [hi|lo] bf16 [2*HID] ----------------
__global__ __launch_bounds__(256) void l2_aug(const float* __restrict__ x,
                                              ushort* __restrict__ out, int M) {
    int wv = threadIdx.x >> 6, lane = threadIdx.x & 63;
    int row = blockIdx.x * 4 + wv;
    if (row >= M) return;
    const float4* p = (const float4*)(x + (size_t)row * HID);
    float4 a = p[lane * 2], b = p[lane * 2 + 1];
    float sq = a.x*a.x + a.y*a.y + a.z*a.z + a.w*a.w
             + b.x*b.x + b.y*b.y + b.z*b.z + b.w*b.w;
    #pragma unroll
    for (int o = 32; o > 0; o >>= 1) sq += __shfl_xor(sq, o);
    float n = sqrtf(sq);
    float r = 1.0f / fmaxf(n, 1e-12f);
    store_hilo(out + (size_t)row * (2 * HID), lane,
               a.x * r, a.y * r, a.z * r, a.w * r,
               b.x * r, b.y * r, b.z * r, b.w * r);
}

// ---------------- top-8 per row with lowest-index tie-break ----------------
__global__ __launch_bounds__(256) void topk_kernel(const float* __restrict__ scores,
                                                   float* __restrict__ out_scores,
                                                   int* __restrict__ out_idx, int N) {
    __shared__ float ls[2048];
    __shared__ int   li[2048];
    const int q   = blockIdx.x;
    const int tid = threadIdx.x;
    const float* row = scores + (size_t)q * N;
    float s[8]; int ix[8];
    #pragma unroll
    for (int i = 0; i < 8; ++i) { s[i] = -1e30f; ix[i] = 0x7fffffff; }
    for (int j = tid; j < N; j += 256) {
        float v = row[j];
        if (v > s[7]) {
            s[7] = v; ix[7] = j;
            #pragma unroll
            for (int t = 7; t > 0; --t) {
                bool sw = (s[t] > s[t-1]) || (s[t] == s[t-1] && ix[t] < ix[t-1]);
                if (sw) {
                    float tv = s[t]; s[t] = s[t-1]; s[t-1] = tv;
                    int   ti = ix[t]; ix[t] = ix[t-1]; ix[t-1] = ti;
                }
            }
        }
    }
    #pragma unroll
    for (int i = 0; i < 8; ++i) { ls[tid * 8 + i] = s[i]; li[tid * 8 + i] = ix[i]; }
    __syncthreads();
    for (int w = 64; w >= 1; w >>= 2) {
        if (tid < w) {
            #pragma unroll
            for (int i = 0; i < 8; ++i) { s[i] = -1e30f; ix[i] = 0x7fffffff; }
            #pragma unroll
            for (int c = 0; c < 32; ++c) {
                float v  = ls[tid * 32 + c];
                int   vi = li[tid * 32 + c];
                bool better = (v > s[7]) || (v == s[7] && vi < ix[7]);
                if (better) {
                    s[7] = v; ix[7] = vi;
                    #pragma unroll
                    for (int t = 7; t > 0; --t) {
                        bool sw = (s[t] > s[t-1]) || (s[t] == s[t-1] && ix[t] < ix[t-1]);
                        if (sw) {
                            float tv = s[t]; s[t] = s[t-1]; s[t-1] = tv;
                            int   ti = ix[t]; ix[t] = ix[t-1]; ix[t-1] = ti;
                        }
                    }
                }
            }
        }
        __syncthreads();
        if (tid < w) {
            #pragma unroll
            for (int i = 0; i < 8; ++i) { ls[tid * 8 + i] = s[i]; li[tid * 8 + i] = ix[i]; }
        }
        __syncthreads();
    }
    if (tid < 8) {
        out_scores[(size_t)q * 8 + tid] = ls[tid];
        out_idx[q * 8 + tid]            = li[tid];
    }
}

// ---------------- gather retrieved docs ----------------
__global__ __launch_bounds__(256) void gather_kernel(const float* __restrict__ docs,
                                                     const int* __restrict__ idx,
                                                     float* __restrict__ out) {
    const int b = blockIdx.x;
    const int d = idx[b];
    const float4* src = (const float4*)(docs + (size_t)d * DTOK * EMB);
    float4*       dst = (float4*)(out + (size_t)b * DTOK * EMB);
    for (int i = threadIdx.x; i < DTOK * EMB / 4; i += 256) dst[i] = src[i];
}

extern "C" void kernel_launch(void* const* d_in, const int* in_sizes, int n_in,
                              void* d_out, int out_size, void* d_ws, size_t ws_size,
                              hipStream_t stream) {
    const float* qe   = (const float*)d_in[0];
    const float* de   = (const float*)d_in[1];
    const float* qW1  = (const float*)d_in[2];
    const float* qb1  = (const float*)d_in[3];
    const float* qW2  = (const float*)d_in[4];
    const float* qb2  = (const float*)d_in[5];
    const float* qg   = (const float*)d_in[6];
    const float* qbe  = (const float*)d_in[7];
    const float* dW1  = (const float*)d_in[8];
    const float* db1  = (const float*)d_in[9];
    const float* dW2  = (const float*)d_in[10];
    const float* db2  = (const float*)d_in[11];
    const float* dg   = (const float*)d_in[12];
    const float* dbe  = (const float*)d_in[13];
    const float* pW   = (const float*)d_in[14];
    const float* pb   = (const float*)d_in[15];
    const float* temp = (const float*)d_in[16];

    float* out = (float*)d_out;

    // ---- workspace carve (~380 MB) ----
    char* w = (char*)d_ws;
    float*  scores = (float*)w;                 w += (size_t)NQ * ND * 4;
    ushort* W1p    = (ushort*)w;                w += (size_t)HID * 2 * EMB * 2;
    ushort* W2p    = (ushort*)w;                w += (size_t)HID * 2 * HID * 2;
    ushort* pWp    = (ushort*)w;                w += (size_t)HID * 2 * HID * 2;
    ushort* QW1p   = (ushort*)w;                w += (size_t)HID * 2 * EMB * 2;
    ushort* QW2p   = (ushort*)w;                w += (size_t)HID * 2 * HID * 2;
    int*    tidx   = (int*)w;                   w += 4096;
    ushort* pooled = (ushort*)w;                w += (size_t)MT * 2 * EMB * 2;      // 154 MB
    ushort* h1a    = (ushort*)w;                w += (size_t)MT * 2 * HID * 2;      // 103 MB
    float*  h2     = (float*)w;                 w += (size_t)MT * HID * 4;          // 103 MB
    ushort* lna    = pooled;   // LN-aug overwrites pooled (dead after GEMM1)
    float*  pproj  = h2;       // GEMM3 out overwrites h2 (dead after ln_aug)
    ushort* Daug   = h1a;      // l2_aug overwrites h1a (dead after GEMM2)
    ushort* qaug   = Daug + (size_t)NDP * 2 * HID;   // query rows inside Daug

    const int GM = (MT + 127) / 128;   // 392 row panels (391 doc + 1 query) — FIXED

    // ---- weight conversion (tiny) ----
    wconv<<<HID, 256, 0, stream>>>(dW1, W1p, EMB);
    wconv<<<HID, 256, 0, stream>>>(dW2, W2p, HID);
    wconv<<<HID, 256, 0, stream>>>(pW,  pWp, HID);
    wconv<<<HID, 256, 0, stream>>>(qW1, QW1p, EMB);
    wconv<<<HID, 256, 0, stream>>>(qW2, QW2p, HID);

    // ---- unified doc+query pipeline ----
    pool_aug_all<<<ND + NQ, 192, 0, stream>>>(de, qe, pooled);
    mfma_gemm2<1><<<dim3(GM, 2), 512, 0, stream>>>(pooled, W1p, QW1p, db1, qb1, h1a, MT, EMB);
    mfma_gemm2<0><<<dim3(GM, 2), 512, 0, stream>>>(h1a, W2p, QW2p, db2, qb2, h2, MT, HID);
    ln_aug<<<(MT + 3) / 4, 256, 0, stream>>>(h2, dg, dbe, qg, qbe, lna, MT);
    mfma_gemm2<0><<<dim3(GM, 2), 512, 0, stream>>>(lna, pWp, pWp, pb, pb, pproj, MT, HID);
    l2_aug<<<(MT + 3) / 4, 256, 0, stream>>>(pproj, Daug, MT);

    // ---- scores: [64, ND] = qaug x Daug^T * (1/T) ----
    mfma_scores<<<dim3(1, (ND + 255) / 256), 512, 0, stream>>>(qaug, Daug, scores,
                                                               NQ, ND, HID, (long)ND, temp);

    // ---- top-k + gather ----
    topk_kernel<<<NQ, 256, 0, stream>>>(scores, out, tidx, ND);
    gather_kernel<<<NQ * 8, 256, 0, stream>>>(de, tidx, out + NQ * 8);
}

// Round 10
// 1298.758 us; speedup vs baseline: 1.3058x; 1.0420x over previous
//
#include <hip/hip_runtime.h>

#define NQ 64
#define ND 50000
#define NDP 50048              // padded doc rows (391 full 128-panels)
#define MT (NDP + NQ)          // 50112 total rows (docs + pad + queries)
#define QTOK 32
#define DTOK 16
#define EMB 768
#define HID 512

typedef short s16x8 __attribute__((ext_vector_type(8)));
typedef float f32x4 __attribute__((ext_vector_type(4)));

// ---------- bf16 helpers (RNE) ----------
__device__ __forceinline__ unsigned short f2bf(float f) {
    union { float f; unsigned u; } x; x.f = f;
    unsigned r = x.u + 0x7fffu + ((x.u >> 16) & 1u);
    return (unsigned short)(r >> 16);
}
__device__ __forceinline__ float bf2f(unsigned short h) {
    union { unsigned u; float f; } x; x.u = ((unsigned)h) << 16;
    return x.f;
}
__device__ __forceinline__ unsigned packhi2(float a, float b) {
    return (unsigned)f2bf(a) | ((unsigned)f2bf(b) << 16);
}
__device__ __forceinline__ unsigned packlo2(float a, float b) {
    unsigned short ha = f2bf(a), hb = f2bf(b);
    return (unsigned)f2bf(a - bf2f(ha)) | ((unsigned)f2bf(b - bf2f(hb)) << 16);
}

__device__ __forceinline__ void gload_lds16(const void* g, void* l) {
    __builtin_amdgcn_global_load_lds(
        (const __attribute__((address_space(1))) void*)g,
        (__attribute__((address_space(3))) void*)l, 16, 0, 0);
}

// ============ storage layout ============
// Augmented tensors: [rows][2K] = [hi(0..K-1) | lo(0..K-1)] bf16 (side-agnostic).
// Logical GEMM K2 = 3K in regions [hiA*hiB | loA*hiB | hiA*loB]:
//   A k-offset: ka = k0 < 2K ? k0 : k0-2K
//   B k-offset: kb = k0 <  K ? k0 : k0-K
// Rows 0..49999 docs, 50000..50047 pad (garbage, never consumed), 50048..50111 queries.
// LN folded into GEMM3: y@pW+pb = rs*(h@W') - rs*mu*u + vv,  W'=diag(g)pW, u=g@pW, vv=beta@pW+pb.
// L2 folded into scores: score = (pq.pd) * rsqrt(n2q) * rsqrt(n2d) / T.

// ---------------- mean-pool (docs + queries) -> [hi|lo] bf16 [2*EMB] ----------------
__global__ void pool_aug_all(const float* __restrict__ de, const float* __restrict__ qe,
                             ushort* __restrict__ out) {
    int blk = blockIdx.x, t = threadIdx.x;  // 192 threads x 4 floats
    const float* src;
    int T;
    size_t orow;
    if (blk < ND) { src = de + (size_t)blk * DTOK * EMB; T = DTOK; orow = blk; }
    else          { int qr = blk - ND; src = qe + (size_t)qr * QTOK * EMB; T = QTOK; orow = NDP + qr; }
    const float4* ip = (const float4*)src + t;
    float4 a = make_float4(0.f, 0.f, 0.f, 0.f);
    for (int i = 0; i < T; ++i) {
        float4 v = ip[(size_t)i * (EMB / 4)];
        a.x += v.x; a.y += v.y; a.z += v.z; a.w += v.w;
    }
    const float s = 1.0f / (float)T;
    float v0 = a.x * s, v1 = a.y * s, v2 = a.z * s, v3 = a.w * s;
    ushort* base = out + orow * (2 * EMB);
    *(uint2*)(base + t * 4)       = make_uint2(packhi2(v0, v1), packhi2(v2, v3));
    *(uint2*)(base + EMB + t * 4) = make_uint2(packlo2(v0, v1), packlo2(v2, v3));
}

// ---------------- weight convert, 6 segments: W[K][512] -> Wp[512][2K] = [hi|lo] ----------------
// seg 4/5 scale rows by dg/qg (LN-gamma folding into pW).
__global__ void wconv_all(const float* __restrict__ dW1, const float* __restrict__ qW1,
                          const float* __restrict__ dW2, const float* __restrict__ qW2,
                          const float* __restrict__ pW,
                          const float* __restrict__ dg, const float* __restrict__ qg,
                          ushort* __restrict__ W1p, ushort* __restrict__ QW1p,
                          ushort* __restrict__ W2p, ushort* __restrict__ QW2p,
                          ushort* __restrict__ W3d, ushort* __restrict__ W3q) {
    int n = blockIdx.x, seg = blockIdx.y;
    const float* W; const float* scale = nullptr; ushort* o; int K;
    switch (seg) {
        case 0:  W = dW1; o = W1p;  K = EMB; break;
        case 1:  W = qW1; o = QW1p; K = EMB; break;
        case 2:  W = dW2; o = W2p;  K = HID; break;
        case 3:  W = qW2; o = QW2p; K = HID; break;
        case 4:  W = pW;  o = W3d;  K = HID; scale = dg; break;
        default: W = pW;  o = W3q;  K = HID; scale = qg; break;
    }
    ushort* base = o + (size_t)n * 2 * K;
    for (int k = threadIdx.x; k < K; k += blockDim.x) {
        float v = W[(size_t)k * HID + n];
        if (scale) v *= scale[k];
        unsigned short hi = f2bf(v);
        base[k]     = hi;
        base[K + k] = f2bf(v - bf2f(hi));
    }
}

// ---------------- u/vv prep: u = g@pW, vv = beta@pW + pb (doc & query) ----------------
__global__ void uv_prep(const float* __restrict__ pW, const float* __restrict__ pb,
                        const float* __restrict__ dg, const float* __restrict__ dbe,
                        const float* __restrict__ qg, const float* __restrict__ qbe,
                        float* __restrict__ ud, float* __restrict__ vvd,
                        float* __restrict__ uq, float* __restrict__ vvq) {
    int n = blockIdx.x;  // 512
    float a = 0.f, b = 0.f, c = 0.f, d = 0.f;
    for (int k = threadIdx.x; k < HID; k += 256) {
        float w = pW[(size_t)k * HID + n];
        a += dg[k] * w; b += dbe[k] * w; c += qg[k] * w; d += qbe[k] * w;
    }
    #pragma unroll
    for (int o = 32; o > 0; o >>= 1) {
        a += __shfl_xor(a, o); b += __shfl_xor(b, o);
        c += __shfl_xor(c, o); d += __shfl_xor(d, o);
    }
    __shared__ float red[4][4];
    int wv = threadIdx.x >> 6, ln = threadIdx.x & 63;
    if (ln == 0) { red[wv][0] = a; red[wv][1] = b; red[wv][2] = c; red[wv][3] = d; }
    __syncthreads();
    if (threadIdx.x == 0) {
        float A = 0, B = 0, C = 0, D = 0;
        #pragma unroll
        for (int i = 0; i < 4; ++i) { A += red[i][0]; B += red[i][1]; C += red[i][2]; D += red[i][3]; }
        ud[n] = A; vvd[n] = B + pb[n]; uq[n] = C; vvq[n] = D + pb[n];
    }
}

// ---------------- MFMA GEMM: 128x256 tile, 8 waves, per-panel weight select ----------------
// MODE 1: relu(acc+bias) -> hi|lo                         (GEMM1)
// MODE 2: raw acc+bias   -> hi|lo + {sum,sumsq} partials  (GEMM2)
// MODE 3: LN-folded: rs*(acc - mu*u) + vv -> hi|lo + norm2 partials  (GEMM3)
template <int MODE>
__global__ __launch_bounds__(512, 4) void mfma_gemm2(const ushort* __restrict__ A,
                                                     const ushort* __restrict__ Bd,
                                                     const ushort* __restrict__ Bq,
                                                     const float* __restrict__ pard,   // bias | u
                                                     const float* __restrict__ parq,
                                                     const float* __restrict__ auxd,   // vv (MODE 3)
                                                     const float* __restrict__ auxq,
                                                     const float2* __restrict__ statsIn,  // sums (MODE 3)
                                                     float2* __restrict__ sumsOut,        // (MODE 2)
                                                     float* __restrict__ normpOut,        // (MODE 3)
                                                     void* __restrict__ out,
                                                     int M, int K) {
    __shared__ ushort As[128 * 64];   // 16KB
    __shared__ ushort Bs[256 * 64];   // 32KB
    __shared__ float redS[4][128];    // 2KB (stats)
    __shared__ float redQ[4][128];    // 2KB
    const int Ks = 2 * K;
    const int bm = blockIdx.x * 128;
    const int bn = blockIdx.y * 256;
    const bool isq = (bm >= NDP);
    const ushort* B = isq ? Bq : Bd;
    const int tid = threadIdx.x;
    const int lane = tid & 63;
    const int wave = tid >> 6;
    const int wr = wave >> 2;
    const int wc = wave & 3;
    f32x4 acc[4][4] = {};

    for (int k0 = 0; k0 < 3 * K; k0 += 64) {
        const int ka = (k0 < 2 * K) ? k0 : k0 - 2 * K;
        const int kb = (k0 < K) ? k0 : k0 - K;
        #pragma unroll
        for (int c = 0; c < 2; ++c) {   // stage A: 16KB
            int idx = c * 512 + tid;
            int row = idx >> 3, s = idx & 7;
            int gr = bm + row; if (gr >= M) gr = M - 1;
            int ks = (s ^ (row & 7)) << 3;
            gload_lds16(A + (size_t)gr * Ks + ka + ks, As + idx * 8);
        }
        #pragma unroll
        for (int c = 0; c < 4; ++c) {   // stage B: 32KB
            int idx = c * 512 + tid;
            int n = idx >> 3, s = idx & 7;
            int ks = (s ^ (n & 7)) << 3;
            gload_lds16(B + (size_t)(bn + n) * Ks + kb + ks, Bs + idx * 8);
        }
        __syncthreads();

        #pragma unroll
        for (int kk = 0; kk < 2; ++kk) {
            const int sp = kk * 4 + (lane >> 4);
            s16x8 a[4], b[4];
            #pragma unroll
            for (int i = 0; i < 4; ++i) {
                int r = wr * 64 + i * 16 + (lane & 15);
                a[i] = *(const s16x8*)(As + r * 64 + ((sp ^ (r & 7)) << 3));
            }
            #pragma unroll
            for (int j = 0; j < 4; ++j) {
                int n = wc * 64 + j * 16 + (lane & 15);
                b[j] = *(const s16x8*)(Bs + n * 64 + ((sp ^ (n & 7)) << 3));
            }
            #pragma unroll
            for (int i = 0; i < 4; ++i)
                #pragma unroll
                for (int j = 0; j < 4; ++j)
                    acc[i][j] = __builtin_amdgcn_mfma_f32_16x16x32_bf16(a[i], b[j], acc[i][j], 0, 0, 0);
        }
        __syncthreads();
    }

    // ---- epilogue; C/D layout: col = bn + wc*64 + j*16 + (lane&15); row = bm + wr*64 + i*16 + (lane>>4)*4 + r
    if (MODE == 1 || MODE == 2) {
        const float* bias = isq ? parq : pard;
        float bv[4];
        #pragma unroll
        for (int j = 0; j < 4; ++j) bv[j] = bias[bn + wc * 64 + j * 16 + (lane & 15)];

        if (MODE == 2) {   // row stats partials (sum, sumsq over this block's 256 cols)
            #pragma unroll
            for (int i = 0; i < 4; ++i)
                #pragma unroll
                for (int r = 0; r < 4; ++r) {
                    float ps = 0.f, pq = 0.f;
                    #pragma unroll
                    for (int j = 0; j < 4; ++j) {
                        float v = acc[i][j][r] + bv[j];
                        ps += v; pq += v * v;
                    }
                    #pragma unroll
                    for (int o = 1; o < 16; o <<= 1) { ps += __shfl_xor(ps, o); pq += __shfl_xor(pq, o); }
                    if ((lane & 15) == 0) {
                        int rl = wr * 64 + i * 16 + ((lane >> 4) << 2) + r;
                        redS[wc][rl] = ps; redQ[wc][rl] = pq;
                    }
                }
            __syncthreads();
            if (tid < 128) {
                float s = redS[0][tid] + redS[1][tid] + redS[2][tid] + redS[3][tid];
                float q = redQ[0][tid] + redQ[1][tid] + redQ[2][tid] + redQ[3][tid];
                int grow = bm + tid;
                if (grow < M) sumsOut[(size_t)grow * 2 + blockIdx.y] = make_float2(s, q);
            }
        }

        #pragma unroll
        for (int j = 0; j < 4; ++j) {
            int col = bn + wc * 64 + j * 16 + (lane & 15);
            #pragma unroll
            for (int i = 0; i < 4; ++i)
                #pragma unroll
                for (int r = 0; r < 4; ++r) {
                    int grow = bm + wr * 64 + i * 16 + ((lane >> 4) << 2) + r;
                    if (grow >= M) continue;
                    float v = acc[i][j][r] + bv[j];
                    if (MODE == 1) v = fmaxf(v, 0.0f);
                    unsigned short hi = f2bf(v);
                    ushort* op = (ushort*)out + (size_t)grow * (2 * HID);
                    op[col]       = hi;
                    op[HID + col] = f2bf(v - bf2f(hi));
                }
        }
    } else {  // MODE 3
        const float* u  = isq ? parq : pard;
        const float* vv = isq ? auxq : auxd;
        float uj[4], vj[4];
        #pragma unroll
        for (int j = 0; j < 4; ++j) {
            int col = bn + wc * 64 + j * 16 + (lane & 15);
            uj[j] = u[col]; vj[j] = vv[col];
        }
        #pragma unroll
        for (int i = 0; i < 4; ++i)
            #pragma unroll
            for (int r = 0; r < 4; ++r) {
                int grow = bm + wr * 64 + i * 16 + ((lane >> 4) << 2) + r;
                int gsr  = grow < M ? grow : M - 1;
                float2 p0 = statsIn[(size_t)gsr * 2 + 0];
                float2 p1 = statsIn[(size_t)gsr * 2 + 1];
                float s  = p0.x + p1.x, qq = p0.y + p1.y;
                float mu  = s * (1.0f / 512.0f);
                float var = qq * (1.0f / 512.0f) - mu * mu;
                float rs  = rsqrtf(var + 1e-5f);
                float ps = 0.f;
                #pragma unroll
                for (int j = 0; j < 4; ++j) {
                    float val = rs * (acc[i][j][r] - mu * uj[j]) + vj[j];
                    ps += val * val;
                    if (grow < M) {
                        int col = bn + wc * 64 + j * 16 + (lane & 15);
                        unsigned short hi = f2bf(val);
                        ushort* op = (ushort*)out + (size_t)grow * (2 * HID);
                        op[col]       = hi;
                        op[HID + col] = f2bf(val - bf2f(hi));
                    }
                }
                #pragma unroll
                for (int o = 1; o < 16; o <<= 1) ps += __shfl_xor(ps, o);
                if ((lane & 15) == 0) {
                    int rl = wr * 64 + i * 16 + ((lane >> 4) << 2) + r;
                    redS[wc][rl] = ps;
                }
            }
        __syncthreads();
        if (tid < 128) {
            float s = redS[0][tid] + redS[1][tid] + redS[2][tid] + redS[3][tid];
            int grow = bm + tid;
            if (grow < M) normpOut[(size_t)grow * 2 + blockIdx.y] = s;
        }
    }
}

// ---------------- scores MFMA GEMM: A [64][2K] (rows rowOff..), B [ND][2K]; L2 applied via normp ----------------
__global__ __launch_bounds__(512, 4) void mfma_scores(const ushort* __restrict__ A,
                                                      const ushort* __restrict__ B,
                                                      const float* __restrict__ normp,
                                                      float* __restrict__ out,
                                                      int M, int N_B, int K, long ldo,
                                                      const float* __restrict__ temp, int rowOff) {
    __shared__ ushort As[128 * 64];
    __shared__ ushort Bs[256 * 64];
    const int Ks = 2 * K;
    const int bm = blockIdx.x * 128;
    const int bn = blockIdx.y * 256;
    const int tid = threadIdx.x;
    const int lane = tid & 63;
    const int wave = tid >> 6;
    const int wr = wave >> 2;
    const int wc = wave & 3;
    f32x4 acc[4][4] = {};

    for (int k0 = 0; k0 < 3 * K; k0 += 64) {
        const int ka = (k0 < 2 * K) ? k0 : k0 - 2 * K;
        const int kb = (k0 < K) ? k0 : k0 - K;
        #pragma unroll
        for (int c = 0; c < 2; ++c) {
            int idx = c * 512 + tid;
            int row = idx >> 3, s = idx & 7;
            int gr = bm + row; if (gr >= M) gr = M - 1;
            int ks = (s ^ (row & 7)) << 3;
            gload_lds16(A + (size_t)gr * Ks + ka + ks, As + idx * 8);
        }
        #pragma unroll
        for (int c = 0; c < 4; ++c) {
            int idx = c * 512 + tid;
            int n = idx >> 3, s = idx & 7;
            int gn = bn + n; if (gn >= N_B) gn = N_B - 1;
            int ks = (s ^ (n & 7)) << 3;
            gload_lds16(B + (size_t)gn * Ks + kb + ks, Bs + idx * 8);
        }
        __syncthreads();

        #pragma unroll
        for (int kk = 0; kk < 2; ++kk) {
            const int sp = kk * 4 + (lane >> 4);
            s16x8 a[4], b[4];
            #pragma unroll
            for (int i = 0; i < 4; ++i) {
                int r = wr * 64 + i * 16 + (lane & 15);
                a[i] = *(const s16x8*)(As + r * 64 + ((sp ^ (r & 7)) << 3));
            }
            #pragma unroll
            for (int j = 0; j < 4; ++j) {
                int n = wc * 64 + j * 16 + (lane & 15);
                b[j] = *(const s16x8*)(Bs + n * 64 + ((sp ^ (n & 7)) << 3));
            }
            #pragma unroll
            for (int i = 0; i < 4; ++i)
                #pragma unroll
                for (int j = 0; j < 4; ++j)
                    acc[i][j] = __builtin_amdgcn_mfma_f32_16x16x32_bf16(a[i], b[j], acc[i][j], 0, 0, 0);
        }
        __syncthreads();
    }

    float invT = 1.0f / temp[0];
    float rB[4];
    #pragma unroll
    for (int j = 0; j < 4; ++j) {
        int gcol = bn + wc * 64 + j * 16 + (lane & 15);
        int gc = gcol < N_B ? gcol : N_B - 1;
        float n2 = normp[(size_t)gc * 2] + normp[(size_t)gc * 2 + 1];
        rB[j] = 1.0f / fmaxf(sqrtf(n2), 1e-12f);
    }
    #pragma unroll
    for (int i = 0; i < 4; ++i)
        #pragma unroll
        for (int r = 0; r < 4; ++r) {
            int grow = bm + wr * 64 + i * 16 + ((lane >> 4) << 2) + r;
            int gr = grow < M ? grow : M - 1;
            float n2a = normp[(size_t)(rowOff + gr) * 2] + normp[(size_t)(rowOff + gr) * 2 + 1];
            float rA = 1.0f / fmaxf(sqrtf(n2a), 1e-12f);
            #pragma unroll
            for (int j = 0; j < 4; ++j) {
                int gcol = bn + wc * 64 + j * 16 + (lane & 15);
                if (grow < M && gcol < N_B)
                    out[(size_t)grow * ldo + gcol] = acc[i][j][r] * rA * rB[j] * invT;
            }
        }
}

// ---------------- top-8 per row with lowest-index tie-break ----------------
__global__ __launch_bounds__(256) void topk_kernel(const float* __restrict__ scores,
                                                   float* __restrict__ out_scores,
                                                   int* __restrict__ out_idx, int N) {
    __shared__ float ls[2048];
    __shared__ int   li[2048];
    const int q   = blockIdx.x;
    const int tid = threadIdx.x;
    const float* row = scores + (size_t)q * N;
    float s[8]; int ix[8];
    #pragma unroll
    for (int i = 0; i < 8; ++i) { s[i] = -1e30f; ix[i] = 0x7fffffff; }
    for (int j = tid; j < N; j += 256) {
        float v = row[j];
        if (v > s[7]) {
            s[7] = v; ix[7] = j;
            #pragma unroll
            for (int t = 7; t > 0; --t) {
                bool sw = (s[t] > s[t-1]) || (s[t] == s[t-1] && ix[t] < ix[t-1]);
                if (sw) {
                    float tv = s[t]; s[t] = s[t-1]; s[t-1] = tv;
                    int   ti = ix[t]; ix[t] = ix[t-1]; ix[t-1] = ti;
                }
            }
        }
    }
    #pragma unroll
    for (int i = 0; i < 8; ++i) { ls[tid * 8 + i] = s[i]; li[tid * 8 + i] = ix[i]; }
    __syncthreads();
    for (int w = 64; w >= 1; w >>= 2) {
        if (tid < w) {
            #pragma unroll
            for (int i = 0; i < 8; ++i) { s[i] = -1e30f; ix[i] = 0x7fffffff; }
            #pragma unroll
            for (int c = 0; c < 32; ++c) {
                float v  = ls[tid * 32 + c];
                int   vi = li[tid * 32 + c];
                bool better = (v > s[7]) || (v == s[7] && vi < ix[7]);
                if (better) {
                    s[7] = v; ix[7] = vi;
                    #pragma unroll
                    for (int t = 7; t > 0; --t) {
                        bool sw = (s[t] > s[t-1]) || (s[t] == s[t-1] && ix[t] < ix[t-1]);
                        if (sw) {
                            float tv = s[t]; s[t] = s[t-1]; s[t-1] = tv;
                            int   ti = ix[t]; ix[t] = ix[t-1]; ix[t-1] = ti;
                        }
                    }
                }
            }
        }
        __syncthreads();
        if (tid < w) {
            #pragma unroll
            for (int i = 0; i < 8; ++i) { ls[tid * 8 + i] = s[i]; li[tid * 8 + i] = ix[i]; }
        }
        __syncthreads();
    }
    if (tid < 8) {
        out_scores[(size_t)q * 8 + tid] = ls[tid];
        out_idx[q * 8 + tid]            = li[tid];
    }
}

// ---------------- gather retrieved docs ----------------
__global__ __launch_bounds__(256) void gather_kernel(const float* __restrict__ docs,
                                                     const int* __restrict__ idx,
                                                     float* __restrict__ out) {
    const int b = blockIdx.x;
    const int d = idx[b];
    const float4* src = (const float4*)(docs + (size_t)d * DTOK * EMB);
    float4*       dst = (float4*)(out + (size_t)b * DTOK * EMB);
    for (int i = threadIdx.x; i < DTOK * EMB / 4; i += 256) dst[i] = src[i];
}

extern "C" void kernel_launch(void* const* d_in, const int* in_sizes, int n_in,
                              void* d_out, int out_size, void* d_ws, size_t ws_size,
                              hipStream_t stream) {
    const float* qe   = (const float*)d_in[0];
    const float* de   = (const float*)d_in[1];
    const float* qW1  = (const float*)d_in[2];
    const float* qb1  = (const float*)d_in[3];
    const float* qW2  = (const float*)d_in[4];
    const float* qb2  = (const float*)d_in[5];
    const float* qg   = (const float*)d_in[6];
    const float* qbe  = (const float*)d_in[7];
    const float* dW1  = (const float*)d_in[8];
    const float* db1  = (const float*)d_in[9];
    const float* dW2  = (const float*)d_in[10];
    const float* db2  = (const float*)d_in[11];
    const float* dg   = (const float*)d_in[12];
    const float* dbe  = (const float*)d_in[13];
    const float* pW   = (const float*)d_in[14];
    const float* pb   = (const float*)d_in[15];
    const float* temp = (const float*)d_in[16];

    float* out = (float*)d_out;

    // ---- workspace carve (~380 MB) ----
    char* w = (char*)d_ws;
    float*  scores = (float*)w;                 w += (size_t)NQ * ND * 4;
    ushort* W1p    = (ushort*)w;                w += (size_t)HID * 2 * EMB * 2;
    ushort* W2p    = (ushort*)w;                w += (size_t)HID * 2 * HID * 2;
    ushort* W3d    = (ushort*)w;                w += (size_t)HID * 2 * HID * 2;
    ushort* QW1p   = (ushort*)w;                w += (size_t)HID * 2 * EMB * 2;
    ushort* QW2p   = (ushort*)w;                w += (size_t)HID * 2 * HID * 2;
    ushort* W3q    = (ushort*)w;                w += (size_t)HID * 2 * HID * 2;
    float*  ud     = (float*)w;                 w += HID * 4;
    float*  vvd    = (float*)w;                 w += HID * 4;
    float*  uq     = (float*)w;                 w += HID * 4;
    float*  vvq    = (float*)w;                 w += HID * 4;
    float2* sums   = (float2*)w;                w += (size_t)MT * 2 * 8;           // 802 KB
    float*  normp  = (float*)w;                 w += (size_t)MT * 2 * 4;           // 401 KB
    int*    tidx   = (int*)w;                   w += 4096;
    ushort* pooled = (ushort*)w;                w += (size_t)MT * 2 * EMB * 2;     // 154 MB
    ushort* h1a    = (ushort*)w;                w += (size_t)MT * 2 * HID * 2;     // 103 MB
    ushort* h2a    = pooled;   // GEMM2 raw output overwrites pooled (dead after GEMM1)
    ushort* Daug   = h1a;      // GEMM3 output overwrites h1a (dead after GEMM2)
    ushort* qaug   = Daug + (size_t)NDP * 2 * HID;   // query rows inside Daug

    const int GM = (MT + 127) / 128;   // 392 row panels (391 doc + 1 query)

    // ---- weight conversion + LN-fold prep (tiny, 2 launches) ----
    wconv_all<<<dim3(512, 6), 256, 0, stream>>>(dW1, qW1, dW2, qW2, pW, dg, qg,
                                                W1p, QW1p, W2p, QW2p, W3d, W3q);
    uv_prep<<<512, 256, 0, stream>>>(pW, pb, dg, dbe, qg, qbe, ud, vvd, uq, vvq);

    // ---- unified doc+query pipeline ----
    pool_aug_all<<<ND + NQ, 192, 0, stream>>>(de, qe, pooled);
    mfma_gemm2<1><<<dim3(GM, 2), 512, 0, stream>>>(pooled, W1p, QW1p, db1, qb1,
                                                   nullptr, nullptr, nullptr, nullptr, nullptr,
                                                   h1a, MT, EMB);
    mfma_gemm2<2><<<dim3(GM, 2), 512, 0, stream>>>(h1a, W2p, QW2p, db2, qb2,
                                                   nullptr, nullptr, nullptr, sums, nullptr,
                                                   h2a, MT, HID);
    mfma_gemm2<3><<<dim3(GM, 2), 512, 0, stream>>>(h2a, W3d, W3q, ud, uq,
                                                   vvd, vvq, sums, nullptr, normp,
                                                   Daug, MT, HID);

    // ---- scores: [64, ND] = (qaug x Daug^T) scaled by rsqrt norms / T ----
    mfma_scores<<<dim3(1, (ND + 255) / 256), 512, 0, stream>>>(qaug, Daug, normp, scores,
                                                               NQ, ND, HID, (long)ND, temp, NDP);

    // ---- top-k + gather ----
    topk_kernel<<<NQ, 256, 0, stream>>>(scores, out, tidx, ND);
    gather_kernel<<<NQ * 8, 256, 0, stream>>>(de, tidx, out + NQ * 8);
}